// Round 1
// baseline (891.082 us; speedup 1.0000x reference)
//
#include <hip/hip_runtime.h>

typedef __attribute__((ext_vector_type(8))) short short8;
typedef __attribute__((ext_vector_type(4))) short short4v;
typedef __attribute__((ext_vector_type(4))) float f32x4;

#define B_SZ 4
#define NSEQ 2048
#define DIM  768
#define NH   8
#define DH   96

__device__ __forceinline__ unsigned short f2bf(float f) {
  unsigned int u = __float_as_uint(f);
  u += 0x7fffu + ((u >> 16) & 1u);   // RNE
  return (unsigned short)(u >> 16);
}

__device__ __forceinline__ void glds16(const void* g, void* l) {
  __builtin_amdgcn_global_load_lds((const __attribute__((address_space(1))) void*)g,
                                   (__attribute__((address_space(3))) void*)l, 16, 0, 0);
}

// ---------------- fp32 -> bf16 bulk convert (x) ----------------
__global__ __launch_bounds__(256) void cvt_x_kernel(const float* __restrict__ x,
                                                    unsigned short* __restrict__ xb) {
  int i = blockIdx.x * 256 + threadIdx.x;      // one float4 per thread
  float4 v = ((const float4*)x)[i];
  ushort4 o;
  o.x = f2bf(v.x); o.y = f2bf(v.y); o.z = f2bf(v.z); o.w = f2bf(v.w);
  ((ushort4*)xb)[i] = o;
}

// ---------------- transpose + convert weights: W[768][ncols] -> WT[ncols][768] bf16 ----------------
__global__ __launch_bounds__(256) void transpose_cvt_kernel(const float* __restrict__ W,
                                                            unsigned short* __restrict__ WT,
                                                            int ncols) {
  __shared__ float tile[32][33];
  int tx = threadIdx.x, ty = threadIdx.y;      // 32 x 8
  int c0 = blockIdx.x * 32;                    // along ncols
  int r0 = blockIdx.y * 32;                    // along 768
  for (int i = 0; i < 4; i++)
    tile[ty + i * 8][tx] = W[(size_t)(r0 + ty + i * 8) * ncols + c0 + tx];
  __syncthreads();
  for (int i = 0; i < 4; i++)
    WT[(size_t)(c0 + ty + i * 8) * 768 + r0 + tx] = f2bf(tile[tx][ty + i * 8]);
}

// ---------------- m97-style bf16 GEMM, A[M][768] @ Bt[N][768]^T, 128x128 tile ----------------
// EPI 0: scatter epilogue -> Q (scaled), K, V^T   EPI 1: +bias, fp32 out
template <int EPI>
__global__ __launch_bounds__(256, 2) void gemm_bt(
    const unsigned short* __restrict__ A, const unsigned short* __restrict__ Bt,
    unsigned short* __restrict__ qo, unsigned short* __restrict__ ko,
    unsigned short* __restrict__ vo, float* __restrict__ fo,
    const float* __restrict__ bias)
{
  __shared__ unsigned short As[128 * 32];
  __shared__ unsigned short Bs[128 * 32];
  const int t = threadIdx.x;
  const int w = t >> 6, lane = t & 63;
  const int l15 = lane & 15, qd = lane >> 4;
  const int m0 = blockIdx.y * 128, n0 = blockIdx.x * 128;
  const int wm = (w >> 1) * 64, wn = (w & 1) * 64;

  // staging: per call one wave fills a 16-row x 32-col chunk (1KB), lds = base + lane*16
  const int sr = lane >> 2;               // row within chunk
  const int sc = (lane & 3) * 8;          // col (shorts)
  const unsigned short* ga = A  + (size_t)(m0 + w * 16 + sr) * DIM + sc;
  const unsigned short* gb = Bt + (size_t)(n0 + w * 16 + sr) * DIM + sc;

  f32x4 acc[4][4] = {};

  for (int k0 = 0; k0 < DIM; k0 += 32) {
    glds16(ga + k0,            &As[w * 512]);
    glds16(ga + 64 * DIM + k0, &As[(4 + w) * 512]);
    glds16(gb + k0,            &Bs[w * 512]);
    glds16(gb + 64 * DIM + k0, &Bs[(4 + w) * 512]);
    __syncthreads();
    short8 af[4], bfr[4];
    for (int i = 0; i < 4; i++)
      af[i]  = *(const short8*)&As[(wm + i * 16 + l15) * 32 + qd * 8];
    for (int i = 0; i < 4; i++)
      bfr[i] = *(const short8*)&Bs[(wn + i * 16 + l15) * 32 + qd * 8];
    for (int mi = 0; mi < 4; mi++)
      for (int ni = 0; ni < 4; ni++)
        acc[mi][ni] = __builtin_amdgcn_mfma_f32_16x16x32_bf16(af[mi], bfr[ni], acc[mi][ni], 0, 0, 0);
    __syncthreads();
  }

  for (int mi = 0; mi < 4; mi++)
    for (int ni = 0; ni < 4; ni++)
      for (int r = 0; r < 4; r++) {
        int row = m0 + wm + mi * 16 + qd * 4 + r;
        int col = n0 + wn + ni * 16 + l15;
        float v = acc[mi][ni][r];
        if (EPI == 0) {
          int b = row >> 11, n = row & 2047;
          int s = col / DIM;
          int rem = col - s * DIM;
          int hh = rem / DH;
          int c = rem - hh * DH;
          size_t bh = (size_t)(b * NH + hh);
          if (s == 0)      qo[(bh * NSEQ + n) * DH + c] = f2bf(v * 0.10206207261596577f); // dh^-1/2 folded in
          else if (s == 1) ko[(bh * NSEQ + n) * DH + c] = f2bf(v);
          else             vo[(bh * DH + c) * NSEQ + n] = f2bf(v);   // V stored transposed [b,h,c,n]
        } else {
          fo[(size_t)row * DIM + col] = v + bias[col];
        }
      }
}

// ---------------- flash attention: one block per (b, h, 128-query tile) ----------------
// LDS strides padded to avoid bank conflicts; K-tile buffer reused for per-wave P slabs.
__global__ __launch_bounds__(256, 2) void flash_kernel(
    const unsigned short* __restrict__ Qb, const unsigned short* __restrict__ Kb,
    const unsigned short* __restrict__ Vtb, unsigned short* __restrict__ Z)
{
  constexpr int KSTR = 104;   // 96 + 8  (208B rows: conflict-free b128 reads)
  constexpr int VSTR = 136;   // 128 + 8 (272B rows)
  constexpr int PSTR = 132;   // 264B rows: conflict-free u16 writes + b64 reads
  __shared__ unsigned short Ks[128 * KSTR];   // 26624 B (Q staging / K tile / P slabs)
  __shared__ unsigned short Vs[96 * VSTR];    // 26112 B

  const int t = threadIdx.x, w = t >> 6, lane = t & 63;
  const int l15 = lane & 15, qd = lane >> 4;
  const int qt = blockIdx.x, h = blockIdx.y, b = blockIdx.z;
  const size_t bh = (size_t)(b * NH + h);
  const unsigned short* Qg = Qb  + (bh * NSEQ + (size_t)qt * 128) * DH;
  const unsigned short* Kg = Kb  + bh * NSEQ * DH;
  const unsigned short* Vg = Vtb + bh * DH * NSEQ;

  // ---- stage Q tile (128 x 96) into Ks, pull register-resident Q fragments ----
  for (int i = 0; i < 6; i++) {
    int idx = t + i * 256;
    int rr = idx / 12, oo = idx - rr * 12;
    *((float4*)(Ks + rr * KSTR) + oo) = *((const float4*)(Qg + rr * DH) + oo);
  }
  __syncthreads();
  short8 qa[2][3];
  for (int fq = 0; fq < 2; fq++)
    for (int ks = 0; ks < 3; ks++)
      qa[fq][ks] = *(const short8*)&Ks[(w * 32 + fq * 16 + l15) * KSTR + ks * 32 + qd * 8];

  f32x4 o[2][6] = {};
  float mprev[2][4], lsum[2][4];
  for (int i = 0; i < 2; i++)
    for (int r = 0; r < 4; r++) { mprev[i][r] = -3.0e38f; lsum[i][r] = 0.f; }

  unsigned short* Ps = Ks + w * (16 * PSTR);   // per-wave 16x132 slab, 4*4224B <= Ks size

  for (int kt = 0; kt < 16; kt++) {
    __syncthreads();   // all waves done with Ks(P/Q) + Vs of previous iteration
    const unsigned short* Kt = Kg + (size_t)kt * 128 * DH;
    for (int i = 0; i < 6; i++) {
      int idx = t + i * 256;
      int rr = idx / 12, oo = idx - rr * 12;
      *((float4*)(Ks + rr * KSTR) + oo) = *((const float4*)(Kt + rr * DH) + oo);
    }
    const unsigned short* Vtile = Vg + kt * 128;
    for (int i = 0; i < 6; i++) {
      int idx = t + i * 256;
      int rr = idx >> 4, oo = idx & 15;
      *((float4*)(Vs + rr * VSTR) + oo) = *((const float4*)(Vtile + (size_t)rr * NSEQ) + oo);
    }
    __syncthreads();

    // ---- S = (Q*scale) K^T : wave owns 32 q rows x 128 keys ----
    f32x4 s[2][8] = {};
    for (int ks = 0; ks < 3; ks++)
      for (int fk = 0; fk < 8; fk++) {
        short8 kf = *(const short8*)&Ks[(fk * 16 + l15) * KSTR + ks * 32 + qd * 8];
        s[0][fk] = __builtin_amdgcn_mfma_f32_16x16x32_bf16(qa[0][ks], kf, s[0][fk], 0, 0, 0);
        s[1][fk] = __builtin_amdgcn_mfma_f32_16x16x32_bf16(qa[1][ks], kf, s[1][fk], 0, 0, 0);
      }
    __syncthreads();   // all waves done reading Ks -> safe to overwrite with P

    for (int fq = 0; fq < 2; fq++) {
      for (int r = 0; r < 4; r++) {
        float mx = s[fq][0][r];
        for (int fk = 1; fk < 8; fk++) mx = fmaxf(mx, s[fq][fk][r]);
        for (int off = 1; off < 16; off <<= 1) mx = fmaxf(mx, __shfl_xor(mx, off, 64));
        float mnew = fmaxf(mprev[fq][r], mx);
        float alpha = __expf(mprev[fq][r] - mnew);
        mprev[fq][r] = mnew;
        float sum = 0.f;
        for (int fk = 0; fk < 8; fk++) {
          float p = __expf(s[fq][fk][r] - mnew);
          sum += p;
          Ps[(qd * 4 + r) * PSTR + fk * 16 + l15] = f2bf(p);   // C/D layout -> row-major P
        }
        for (int off = 1; off < 16; off <<= 1) sum += __shfl_xor(sum, off, 64);
        lsum[fq][r] = lsum[fq][r] * alpha + sum;
        for (int fc = 0; fc < 6; fc++) o[fq][fc][r] *= alpha;
      }
      asm volatile("s_waitcnt lgkmcnt(0)" ::: "memory");  // P writes -> A-frag reads (wave-private)
      for (int ks = 0; ks < 4; ks++) {
        union { short4v hlf[2]; short8 v8; } u;
        int poff = l15 * PSTR + ks * 32 + qd * 8;
        u.hlf[0] = *(const short4v*)&Ps[poff];
        u.hlf[1] = *(const short4v*)&Ps[poff + 4];
        for (int fc = 0; fc < 6; fc++) {
          short8 vf = *(const short8*)&Vs[(fc * 16 + l15) * VSTR + ks * 32 + qd * 8];
          o[fq][fc] = __builtin_amdgcn_mfma_f32_16x16x32_bf16(u.v8, vf, o[fq][fc], 0, 0, 0);
        }
      }
      asm volatile("s_waitcnt lgkmcnt(0)" ::: "memory");  // fq0 reads done before fq1 overwrites
    }
  }

  // ---- epilogue: O /= l, write Z with the reference's head-mixing reshape folded in ----
  for (int fq = 0; fq < 2; fq++)
    for (int r = 0; r < 4; r++) {
      float inv = 1.0f / lsum[fq][r];
      int q = qt * 128 + w * 32 + fq * 16 + qd * 4 + r;
      size_t zrow = (size_t)b * NSEQ + h * 256 + (q >> 3);
      int d0 = (q & 7) * DH;
      for (int fc = 0; fc < 6; fc++)
        Z[zrow * DIM + d0 + fc * 16 + l15] = f2bf(o[fq][fc][r] * inv);
    }
}

extern "C" void kernel_launch(void* const* d_in, const int* in_sizes, int n_in,
                              void* d_out, int out_size, void* d_ws, size_t ws_size,
                              hipStream_t stream)
{
  (void)in_sizes; (void)n_in; (void)out_size; (void)ws_size;
  const float* x    = (const float*)d_in[0];
  const float* Wqkv = (const float*)d_in[1];
  const float* Wo   = (const float*)d_in[2];
  const float* bo   = (const float*)d_in[3];
  float* out = (float*)d_out;

  unsigned short* ws    = (unsigned short*)d_ws;
  unsigned short* xb    = ws;                              // 8192*768
  unsigned short* wqkvT = xb    + (size_t)8192 * 768;      // 2304*768
  unsigned short* woT   = wqkvT + (size_t)2304 * 768;      // 768*768
  unsigned short* Qw    = woT   + (size_t)768 * 768;       // 4*8*2048*96
  unsigned short* Kw    = Qw    + (size_t)6291456;
  unsigned short* Vw    = Kw    + (size_t)6291456;
  unsigned short* Zw    = Vw    + (size_t)6291456;         // 8192*768

  cvt_x_kernel<<<6144, 256, 0, stream>>>(x, xb);
  transpose_cvt_kernel<<<dim3(72, 24), dim3(32, 8), 0, stream>>>(Wqkv, wqkvT, 2304);
  transpose_cvt_kernel<<<dim3(24, 24), dim3(32, 8), 0, stream>>>(Wo, woT, 768);
  gemm_bt<0><<<dim3(18, 64), 256, 0, stream>>>(xb, wqkvT, Qw, Kw, Vw, nullptr, nullptr);
  flash_kernel<<<dim3(16, 8, 4), 256, 0, stream>>>(Qw, Kw, Vw, Zw);
  gemm_bt<1><<<dim3(6, 64), 256, 0, stream>>>(Zw, woT, nullptr, nullptr, nullptr, out, bo);
}

// Round 2
// 330.046 us; speedup vs baseline: 2.6999x; 2.6999x over previous
//
#include <hip/hip_runtime.h>

typedef __attribute__((ext_vector_type(8))) short short8;
typedef __attribute__((ext_vector_type(4))) short short4v;
typedef __attribute__((ext_vector_type(4))) float f32x4;

#define B_SZ 4
#define NSEQ 2048
#define DIM  768
#define NH   8
#define DH   96

__device__ __forceinline__ unsigned short f2bf(float f) {
  unsigned int u = __float_as_uint(f);
  u += 0x7fffu + ((u >> 16) & 1u);   // RNE
  return (unsigned short)(u >> 16);
}

__device__ __forceinline__ void glds16(const void* g, void* l) {
  __builtin_amdgcn_global_load_lds((const __attribute__((address_space(1))) void*)g,
                                   (__attribute__((address_space(3))) void*)l, 16, 0, 0);
}

// ---------------- fp32 -> bf16 bulk convert (x) ----------------
__global__ __launch_bounds__(256) void cvt_x_kernel(const float* __restrict__ x,
                                                    unsigned short* __restrict__ xb) {
  int i = blockIdx.x * 256 + threadIdx.x;      // one float4 per thread
  float4 v = ((const float4*)x)[i];
  ushort4 o;
  o.x = f2bf(v.x); o.y = f2bf(v.y); o.z = f2bf(v.z); o.w = f2bf(v.w);
  ((ushort4*)xb)[i] = o;
}

// ---------------- transpose + convert weights: W[768][ncols] -> WT[ncols][768] bf16 ----------------
__global__ __launch_bounds__(256) void transpose_cvt_kernel(const float* __restrict__ W,
                                                            unsigned short* __restrict__ WT,
                                                            int ncols) {
  __shared__ float tile[32][33];
  int tx = threadIdx.x, ty = threadIdx.y;      // 32 x 8
  int c0 = blockIdx.x * 32;                    // along ncols
  int r0 = blockIdx.y * 32;                    // along 768
#pragma unroll
  for (int i = 0; i < 4; i++)
    tile[ty + i * 8][tx] = W[(size_t)(r0 + ty + i * 8) * ncols + c0 + tx];
  __syncthreads();
#pragma unroll
  for (int i = 0; i < 4; i++)
    WT[(size_t)(c0 + ty + i * 8) * 768 + r0 + tx] = f2bf(tile[tx][ty + i * 8]);
}

// ---------------- m97-style bf16 GEMM, A[M][768] @ Bt[N][768]^T, 128x128 tile ----------------
// EPI 0: scatter epilogue -> Q (scaled), K, V^T   EPI 1: +bias, fp32 out
template <int EPI>
__global__ __launch_bounds__(256) void gemm_bt(
    const unsigned short* __restrict__ A, const unsigned short* __restrict__ Bt,
    unsigned short* __restrict__ qo, unsigned short* __restrict__ ko,
    unsigned short* __restrict__ vo, float* __restrict__ fo,
    const float* __restrict__ bias)
{
  __shared__ unsigned short As[128 * 32];
  __shared__ unsigned short Bs[128 * 32];
  const int t = threadIdx.x;
  const int w = t >> 6, lane = t & 63;
  const int l15 = lane & 15, qd = lane >> 4;
  const int m0 = blockIdx.y * 128, n0 = blockIdx.x * 128;
  const int wm = (w >> 1) * 64, wn = (w & 1) * 64;

  // staging: per call one wave fills a 16-row x 32-col chunk (1KB), lds = base + lane*16
  const int sr = lane >> 2;               // row within chunk
  const int sc = (lane & 3) * 8;          // col (shorts)
  const unsigned short* ga = A  + (size_t)(m0 + w * 16 + sr) * DIM + sc;
  const unsigned short* gb = Bt + (size_t)(n0 + w * 16 + sr) * DIM + sc;

  f32x4 acc[4][4] = {};

  for (int k0 = 0; k0 < DIM; k0 += 32) {
    glds16(ga + k0,            &As[w * 512]);
    glds16(ga + 64 * DIM + k0, &As[(4 + w) * 512]);
    glds16(gb + k0,            &Bs[w * 512]);
    glds16(gb + 64 * DIM + k0, &Bs[(4 + w) * 512]);
    __syncthreads();
    short8 af[4], bfr[4];
#pragma unroll
    for (int i = 0; i < 4; i++)
      af[i]  = *(const short8*)&As[(wm + i * 16 + l15) * 32 + qd * 8];
#pragma unroll
    for (int i = 0; i < 4; i++)
      bfr[i] = *(const short8*)&Bs[(wn + i * 16 + l15) * 32 + qd * 8];
#pragma unroll
    for (int mi = 0; mi < 4; mi++)
#pragma unroll
      for (int ni = 0; ni < 4; ni++)
        acc[mi][ni] = __builtin_amdgcn_mfma_f32_16x16x32_bf16(af[mi], bfr[ni], acc[mi][ni], 0, 0, 0);
    __syncthreads();
  }

#pragma unroll
  for (int mi = 0; mi < 4; mi++)
#pragma unroll
    for (int ni = 0; ni < 4; ni++)
#pragma unroll
      for (int r = 0; r < 4; r++) {
        int row = m0 + wm + mi * 16 + qd * 4 + r;
        int col = n0 + wn + ni * 16 + l15;
        float v = acc[mi][ni][r];
        if (EPI == 0) {
          int b = row >> 11, n = row & 2047;
          int s = col / DIM;
          int rem = col - s * DIM;
          int hh = rem / DH;
          int c = rem - hh * DH;
          size_t bh = (size_t)(b * NH + hh);
          if (s == 0)      qo[(bh * NSEQ + n) * DH + c] = f2bf(v * 0.10206207261596577f); // dh^-1/2 folded in
          else if (s == 1) ko[(bh * NSEQ + n) * DH + c] = f2bf(v);
          else             vo[(bh * DH + c) * NSEQ + n] = f2bf(v);   // V stored transposed [b,h,c,n]
        } else {
          fo[(size_t)row * DIM + col] = v + bias[col];
        }
      }
}

// ---------------- flash attention: one block per (b, h, 128-query tile) ----------------
// LDS strides padded to avoid bank conflicts; K-tile buffer reused for per-wave P slabs.
__global__ __launch_bounds__(256) void flash_kernel(
    const unsigned short* __restrict__ Qb, const unsigned short* __restrict__ Kb,
    const unsigned short* __restrict__ Vtb, unsigned short* __restrict__ Z)
{
  constexpr int KSTR = 104;   // 96 + 8  (208B rows: conflict-free b128 reads)
  constexpr int VSTR = 136;   // 128 + 8 (272B rows)
  constexpr int PSTR = 132;   // 264B rows: conflict-free u16 writes + b64 reads
  __shared__ unsigned short Ks[128 * KSTR];   // 26624 B (Q staging / K tile / P slabs)
  __shared__ unsigned short Vs[96 * VSTR];    // 26112 B

  const int t = threadIdx.x, w = t >> 6, lane = t & 63;
  const int l15 = lane & 15, qd = lane >> 4;
  const int qt = blockIdx.x, h = blockIdx.y, b = blockIdx.z;
  const size_t bh = (size_t)(b * NH + h);
  const unsigned short* Qg = Qb  + (bh * NSEQ + (size_t)qt * 128) * DH;
  const unsigned short* Kg = Kb  + bh * NSEQ * DH;
  const unsigned short* Vg = Vtb + bh * DH * NSEQ;

  // ---- stage Q tile (128 x 96) into Ks, pull register-resident Q fragments ----
#pragma unroll
  for (int i = 0; i < 6; i++) {
    int idx = t + i * 256;
    int rr = idx / 12, oo = idx - rr * 12;
    *((float4*)(Ks + rr * KSTR) + oo) = *((const float4*)(Qg + rr * DH) + oo);
  }
  __syncthreads();
  short8 qa[2][3];
#pragma unroll
  for (int fq = 0; fq < 2; fq++)
#pragma unroll
    for (int ks = 0; ks < 3; ks++)
      qa[fq][ks] = *(const short8*)&Ks[(w * 32 + fq * 16 + l15) * KSTR + ks * 32 + qd * 8];

  f32x4 o[2][6] = {};
  float mprev[2][4], lsum[2][4];
#pragma unroll
  for (int i = 0; i < 2; i++)
#pragma unroll
    for (int r = 0; r < 4; r++) { mprev[i][r] = -3.0e38f; lsum[i][r] = 0.f; }

  unsigned short* Ps = Ks + w * (16 * PSTR);   // per-wave 16x132 slab, 4*4224B <= Ks size

  for (int kt = 0; kt < 16; kt++) {
    __syncthreads();   // all waves done with Ks(P/Q) + Vs of previous iteration
    const unsigned short* Kt = Kg + (size_t)kt * 128 * DH;
#pragma unroll
    for (int i = 0; i < 6; i++) {
      int idx = t + i * 256;
      int rr = idx / 12, oo = idx - rr * 12;
      *((float4*)(Ks + rr * KSTR) + oo) = *((const float4*)(Kt + rr * DH) + oo);
    }
    const unsigned short* Vtile = Vg + kt * 128;
#pragma unroll
    for (int i = 0; i < 6; i++) {
      int idx = t + i * 256;
      int rr = idx >> 4, oo = idx & 15;
      *((float4*)(Vs + rr * VSTR) + oo) = *((const float4*)(Vtile + (size_t)rr * NSEQ) + oo);
    }
    __syncthreads();

    // ---- S = (Q*scale) K^T : wave owns 32 q rows x 128 keys ----
    f32x4 s[2][8] = {};
#pragma unroll
    for (int ks = 0; ks < 3; ks++)
#pragma unroll
      for (int fk = 0; fk < 8; fk++) {
        short8 kf = *(const short8*)&Ks[(fk * 16 + l15) * KSTR + ks * 32 + qd * 8];
        s[0][fk] = __builtin_amdgcn_mfma_f32_16x16x32_bf16(qa[0][ks], kf, s[0][fk], 0, 0, 0);
        s[1][fk] = __builtin_amdgcn_mfma_f32_16x16x32_bf16(qa[1][ks], kf, s[1][fk], 0, 0, 0);
      }
    __syncthreads();   // all waves done reading Ks -> safe to overwrite with P

#pragma unroll
    for (int fq = 0; fq < 2; fq++) {
#pragma unroll
      for (int r = 0; r < 4; r++) {
        float mx = s[fq][0][r];
#pragma unroll
        for (int fk = 1; fk < 8; fk++) mx = fmaxf(mx, s[fq][fk][r]);
#pragma unroll
        for (int off = 1; off < 16; off <<= 1) mx = fmaxf(mx, __shfl_xor(mx, off, 64));
        float mnew = fmaxf(mprev[fq][r], mx);
        float alpha = __expf(mprev[fq][r] - mnew);
        mprev[fq][r] = mnew;
        float sum = 0.f;
#pragma unroll
        for (int fk = 0; fk < 8; fk++) {
          float p = __expf(s[fq][fk][r] - mnew);
          sum += p;
          Ps[(qd * 4 + r) * PSTR + fk * 16 + l15] = f2bf(p);   // C/D layout -> row-major P
        }
#pragma unroll
        for (int off = 1; off < 16; off <<= 1) sum += __shfl_xor(sum, off, 64);
        lsum[fq][r] = lsum[fq][r] * alpha + sum;
#pragma unroll
        for (int fc = 0; fc < 6; fc++) o[fq][fc][r] *= alpha;
      }
      asm volatile("s_waitcnt lgkmcnt(0)" ::: "memory");  // P writes -> A-frag reads (wave-private)
#pragma unroll
      for (int ks = 0; ks < 4; ks++) {
        union { short4v hlf[2]; short8 v8; } u;
        int poff = l15 * PSTR + ks * 32 + qd * 8;
        u.hlf[0] = *(const short4v*)&Ps[poff];
        u.hlf[1] = *(const short4v*)&Ps[poff + 4];
#pragma unroll
        for (int fc = 0; fc < 6; fc++) {
          short8 vf = *(const short8*)&Vs[(fc * 16 + l15) * VSTR + ks * 32 + qd * 8];
          o[fq][fc] = __builtin_amdgcn_mfma_f32_16x16x32_bf16(u.v8, vf, o[fq][fc], 0, 0, 0);
        }
      }
      asm volatile("s_waitcnt lgkmcnt(0)" ::: "memory");  // fq0 reads done before fq1 overwrites
    }
  }

  // ---- epilogue: O /= l, write Z with the reference's head-mixing reshape folded in ----
#pragma unroll
  for (int fq = 0; fq < 2; fq++)
#pragma unroll
    for (int r = 0; r < 4; r++) {
      float inv = 1.0f / lsum[fq][r];
      int q = qt * 128 + w * 32 + fq * 16 + qd * 4 + r;
      size_t zrow = (size_t)b * NSEQ + h * 256 + (q >> 3);
      int d0 = (q & 7) * DH;
#pragma unroll
      for (int fc = 0; fc < 6; fc++)
        Z[zrow * DIM + d0 + fc * 16 + l15] = f2bf(o[fq][fc][r] * inv);
    }
}

extern "C" void kernel_launch(void* const* d_in, const int* in_sizes, int n_in,
                              void* d_out, int out_size, void* d_ws, size_t ws_size,
                              hipStream_t stream)
{
  (void)in_sizes; (void)n_in; (void)out_size; (void)ws_size;
  const float* x    = (const float*)d_in[0];
  const float* Wqkv = (const float*)d_in[1];
  const float* Wo   = (const float*)d_in[2];
  const float* bo   = (const float*)d_in[3];
  float* out = (float*)d_out;

  unsigned short* ws    = (unsigned short*)d_ws;
  unsigned short* xb    = ws;                              // 8192*768
  unsigned short* wqkvT = xb    + (size_t)8192 * 768;      // 2304*768
  unsigned short* woT   = wqkvT + (size_t)2304 * 768;      // 768*768
  unsigned short* Qw    = woT   + (size_t)768 * 768;       // 4*8*2048*96
  unsigned short* Kw    = Qw    + (size_t)6291456;
  unsigned short* Vw    = Kw    + (size_t)6291456;
  unsigned short* Zw    = Vw    + (size_t)6291456;         // 8192*768

  cvt_x_kernel<<<6144, 256, 0, stream>>>(x, xb);
  transpose_cvt_kernel<<<dim3(72, 24), dim3(32, 8), 0, stream>>>(Wqkv, wqkvT, 2304);
  transpose_cvt_kernel<<<dim3(24, 24), dim3(32, 8), 0, stream>>>(Wo, woT, 768);
  gemm_bt<0><<<dim3(18, 64), 256, 0, stream>>>(xb, wqkvT, Qw, Kw, Vw, nullptr, nullptr);
  flash_kernel<<<dim3(16, 8, 4), 256, 0, stream>>>(Qw, Kw, Vw, Zw);
  gemm_bt<1><<<dim3(6, 64), 256, 0, stream>>>(Zw, woT, nullptr, nullptr, nullptr, out, bo);
}

// Round 4
// 278.233 us; speedup vs baseline: 3.2026x; 1.1862x over previous
//
#include <hip/hip_runtime.h>

typedef __attribute__((ext_vector_type(8))) short short8;
typedef __attribute__((ext_vector_type(4))) float f32x4;
typedef __attribute__((ext_vector_type(4))) _Float16 half4;
typedef __attribute__((ext_vector_type(2))) __fp16 fp16x2;

#define B_SZ 4
#define NSEQ 2048
#define DIM  768
#define NH   8
#define DH   96

__device__ __forceinline__ unsigned short f2bf(float f) {
  unsigned int u = __float_as_uint(f);
  u += 0x7fffu + ((u >> 16) & 1u);   // RNE
  return (unsigned short)(u >> 16);
}

__device__ __forceinline__ float fexp2(float x) {
#if __has_builtin(__builtin_amdgcn_exp2f)
  return __builtin_amdgcn_exp2f(x);
#else
  return exp2f(x);
#endif
}

__device__ __forceinline__ void glds16(const void* g, void* l) {
  __builtin_amdgcn_global_load_lds((const __attribute__((address_space(1))) void*)g,
                                   (__attribute__((address_space(3))) void*)l, 16, 0, 0);
}

// ---------------- fp32 -> bf16 bulk convert (x) ----------------
__global__ __launch_bounds__(256) void cvt_x_kernel(const float* __restrict__ x,
                                                    unsigned short* __restrict__ xb) {
  int i = blockIdx.x * 256 + threadIdx.x;      // one float4 per thread
  float4 v = ((const float4*)x)[i];
  ushort4 o;
  o.x = f2bf(v.x); o.y = f2bf(v.y); o.z = f2bf(v.z); o.w = f2bf(v.w);
  ((ushort4*)xb)[i] = o;
}

// ---------------- transpose + convert weights: W[768][ncols] -> WT[ncols][768] bf16 ----------------
__global__ __launch_bounds__(256) void transpose_cvt_kernel(const float* __restrict__ W,
                                                            unsigned short* __restrict__ WT,
                                                            int ncols) {
  __shared__ float tile[32][33];
  int tx = threadIdx.x, ty = threadIdx.y;      // 32 x 8
  int c0 = blockIdx.x * 32;                    // along ncols
  int r0 = blockIdx.y * 32;                    // along 768
#pragma unroll
  for (int i = 0; i < 4; i++)
    tile[ty + i * 8][tx] = W[(size_t)(r0 + ty + i * 8) * ncols + c0 + tx];
  __syncthreads();
#pragma unroll
  for (int i = 0; i < 4; i++)
    WT[(size_t)(c0 + ty + i * 8) * 768 + r0 + tx] = f2bf(tile[tx][ty + i * 8]);
}

// ---------------- m97-style bf16 GEMM, A[M][768] @ Bt[N][768]^T, 128x128 tile ----------------
// EPI 0: scatter epilogue -> Q (scaled by dh^-0.5*log2e), K (bf16), V^T (fp16)
// EPI 1: +bias, fp32 out
template <int EPI>
__global__ __launch_bounds__(256) void gemm_bt(
    const unsigned short* __restrict__ A, const unsigned short* __restrict__ Bt,
    unsigned short* __restrict__ qo, unsigned short* __restrict__ ko,
    _Float16* __restrict__ vo, float* __restrict__ fo,
    const float* __restrict__ bias)
{
  __shared__ unsigned short As[128 * 32];
  __shared__ unsigned short Bs[128 * 32];
  const int t = threadIdx.x;
  const int w = t >> 6, lane = t & 63;
  const int l15 = lane & 15, qd = lane >> 4;
  const int m0 = blockIdx.y * 128, n0 = blockIdx.x * 128;
  const int wm = (w >> 1) * 64, wn = (w & 1) * 64;

  const int sr = lane >> 2;               // row within 16-row chunk
  const int sc = (lane & 3) * 8;          // col (shorts)
  const unsigned short* ga = A  + (size_t)(m0 + w * 16 + sr) * DIM + sc;
  const unsigned short* gb = Bt + (size_t)(n0 + w * 16 + sr) * DIM + sc;

  f32x4 acc[4][4] = {};

  for (int k0 = 0; k0 < DIM; k0 += 32) {
    glds16(ga + k0,            &As[w * 512]);
    glds16(ga + 64 * DIM + k0, &As[(4 + w) * 512]);
    glds16(gb + k0,            &Bs[w * 512]);
    glds16(gb + 64 * DIM + k0, &Bs[(4 + w) * 512]);
    __syncthreads();
    short8 af[4], bfr[4];
#pragma unroll
    for (int i = 0; i < 4; i++)
      af[i]  = *(const short8*)&As[(wm + i * 16 + l15) * 32 + qd * 8];
#pragma unroll
    for (int i = 0; i < 4; i++)
      bfr[i] = *(const short8*)&Bs[(wn + i * 16 + l15) * 32 + qd * 8];
#pragma unroll
    for (int mi = 0; mi < 4; mi++)
#pragma unroll
      for (int ni = 0; ni < 4; ni++)
        acc[mi][ni] = __builtin_amdgcn_mfma_f32_16x16x32_bf16(af[mi], bfr[ni], acc[mi][ni], 0, 0, 0);
    __syncthreads();
  }

#pragma unroll
  for (int mi = 0; mi < 4; mi++)
#pragma unroll
    for (int ni = 0; ni < 4; ni++)
#pragma unroll
      for (int r = 0; r < 4; r++) {
        int row = m0 + wm + mi * 16 + qd * 4 + r;
        int col = n0 + wn + ni * 16 + l15;
        float v = acc[mi][ni][r];
        if (EPI == 0) {
          int b = row >> 11, n = row & 2047;
          int s = col / DIM;
          int rem = col - s * DIM;
          int hh = rem / DH;
          int c = rem - hh * DH;
          size_t bh = (size_t)(b * NH + hh);
          if (s == 0)      qo[(bh * NSEQ + n) * DH + c] = f2bf(v * 0.1472444679f); // dh^-0.5 * log2(e)
          else if (s == 1) ko[(bh * NSEQ + n) * DH + c] = f2bf(v);
          else             vo[(bh * DH + c) * NSEQ + n] = (_Float16)v;  // V^T fp16 [b,h,c,n]
        } else {
          fo[(size_t)row * DIM + col] = v + bias[col];
        }
      }
}

// ---------------- flash attention v2: S^T formulation, no P round-trip ----------------
// One block per (b, h, 64-query tile). 4 waves, wave owns 16 q rows.
// S^T = K·Q^T  (16x16x32 bf16): C/D frag (col=q, rows=keys) IS the B-operand
// fragment of 16x16x16 f16 MFMA -> P feeds PV^T straight from registers.
// Row-sum l computed by MFMA via ones-A-fragment (o[6]).
__global__ __launch_bounds__(256, 4) void flash_kernel(
    const unsigned short* __restrict__ Qb, const unsigned short* __restrict__ Kb,
    const _Float16* __restrict__ Vtb, unsigned short* __restrict__ Z)
{
  constexpr int VSTR = 72;                     // 144B rows: f4-aligned staging
  __shared__ unsigned short Ks[64 * 96];       // 12288 B (K tile; Q staging first)
  __shared__ _Float16 Vs[96 * VSTR];           // 13824 B (V^T tile [c][k])

  const int t = threadIdx.x, w = t >> 6, lane = t & 63;
  const int l15 = lane & 15, qd = lane >> 4;
  const int qt = blockIdx.x, h = blockIdx.y, b = blockIdx.z;
  const size_t bh = (size_t)(b * NH + h);
  const unsigned short* Qg = Qb + (bh * NSEQ + (size_t)qt * 64) * DH;
  const unsigned short* Kg = Kb + bh * NSEQ * DH;
  const _Float16*       Vg = Vtb + bh * (size_t)DH * NSEQ;

  // ---- stage Q tile (64x96 bf16, globally contiguous 12288 B) via global_load_lds ----
#pragma unroll
  for (int i = 0; i < 3; i++)
    glds16(Qg + w * 1536 + i * 512 + lane * 8, &Ks[w * 1536 + i * 512]);
  __syncthreads();
  short8 qa[3];
#pragma unroll
  for (int ks = 0; ks < 3; ks++)
    qa[ks] = *(const short8*)&Ks[(w * 16 + l15) * 96 + ks * 32 + qd * 8];

  f32x4 o[7] = {};                             // o[0..5]=O^T frags, o[6]=row-sum (ones trick)
  float mprev = -1e30f;                        // per-lane state: q = l15 (log2 domain)
  const half4 onef = {(_Float16)1.f, (_Float16)1.f, (_Float16)1.f, (_Float16)1.f};

  for (int kt = 0; kt < 32; kt++) {
    __syncthreads();                           // prev iter done reading Ks/Vs (and Q frags)
    const unsigned short* Kt = Kg + (size_t)kt * 64 * DH;   // contiguous 12288 B
#pragma unroll
    for (int i = 0; i < 3; i++)
      glds16(Kt + w * 1536 + i * 512 + lane * 8, &Ks[w * 1536 + i * 512]);
    const _Float16* Vt = Vg + kt * 64;
#pragma unroll
    for (int i = 0; i < 3; i++) {
      int idx = t + i * 256;
      int r = idx >> 3, oo = idx & 7;          // 96 rows x 8 float4
      *(float4*)&Vs[r * VSTR + oo * 8] = *(const float4*)(Vt + (size_t)r * NSEQ + oo * 8);
    }
    __syncthreads();

    // ---- S^T = K·Q^T : lane (qd,l15) gets keys fk*16+qd*4+r for q=l15 ----
    f32x4 s[4] = {};
#pragma unroll
    for (int ks = 0; ks < 3; ks++)
#pragma unroll
      for (int fk = 0; fk < 4; fk++) {
        short8 kf = *(const short8*)&Ks[(fk * 16 + l15) * 96 + ks * 32 + qd * 8];
        s[fk] = __builtin_amdgcn_mfma_f32_16x16x32_bf16(kf, qa[ks], s[fk], 0, 0, 0);
      }

    // ---- online softmax, log2 domain, 1 scalar state per lane ----
    float mx = fmaxf(fmaxf(s[0][0], s[0][1]), fmaxf(s[0][2], s[0][3]));
#pragma unroll
    for (int fk = 1; fk < 4; fk++)
      mx = fmaxf(mx, fmaxf(fmaxf(s[fk][0], s[fk][1]), fmaxf(s[fk][2], s[fk][3])));
    mx = fmaxf(mx, __shfl_xor(mx, 16, 64));
    mx = fmaxf(mx, __shfl_xor(mx, 32, 64));
    float mnew = fmaxf(mprev, mx);
    float alpha = fexp2(mprev - mnew);
    mprev = mnew;

    half4 pf[4];
#pragma unroll
    for (int fk = 0; fk < 4; fk++) {
      union { fp16x2 h2[2]; half4 h4; } u;
      u.h2[0] = __builtin_amdgcn_cvt_pkrtz(fexp2(s[fk][0] - mnew), fexp2(s[fk][1] - mnew));
      u.h2[1] = __builtin_amdgcn_cvt_pkrtz(fexp2(s[fk][2] - mnew), fexp2(s[fk][3] - mnew));
      pf[fk] = u.h4;
    }
#pragma unroll
    for (int i = 0; i < 7; i++) o[i] = o[i] * alpha;

    // ---- O^T += V^T · P^T  (16x16x16 f16, P straight from registers) ----
#pragma unroll
    for (int fk = 0; fk < 4; fk++) {
#pragma unroll
      for (int fc = 0; fc < 6; fc++) {
        half4 vf = *(const half4*)&Vs[(fc * 16 + l15) * VSTR + fk * 16 + qd * 4];
        o[fc] = __builtin_amdgcn_mfma_f32_16x16x16f16(vf, pf[fk], o[fc], 0, 0, 0);
      }
      o[6] = __builtin_amdgcn_mfma_f32_16x16x16f16(onef, pf[fk], o[6], 0, 0, 0);
    }
  }

  // ---- epilogue: O/l, write Z with head-mixing reshape folded in ----
  float inv = 1.0f / o[6][0];                  // all rows of ones-frag equal the row-sum
  int q = qt * 64 + w * 16 + l15;
  size_t zbase = ((size_t)b * NSEQ + h * 256 + (q >> 3)) * DIM + (q & 7) * DH;
#pragma unroll
  for (int fc = 0; fc < 6; fc++)
#pragma unroll
    for (int r = 0; r < 4; r += 2) {
      unsigned int pkd = (unsigned int)f2bf(o[fc][r] * inv)
                       | ((unsigned int)f2bf(o[fc][r + 1] * inv) << 16);
      *(unsigned int*)&Z[zbase + fc * 16 + qd * 4 + r] = pkd;
    }
}

extern "C" void kernel_launch(void* const* d_in, const int* in_sizes, int n_in,
                              void* d_out, int out_size, void* d_ws, size_t ws_size,
                              hipStream_t stream)
{
  (void)in_sizes; (void)n_in; (void)out_size; (void)ws_size;
  const float* x    = (const float*)d_in[0];
  const float* Wqkv = (const float*)d_in[1];
  const float* Wo   = (const float*)d_in[2];
  const float* bo   = (const float*)d_in[3];
  float* out = (float*)d_out;

  unsigned short* ws    = (unsigned short*)d_ws;
  unsigned short* xb    = ws;                              // 8192*768
  unsigned short* wqkvT = xb    + (size_t)8192 * 768;      // 2304*768
  unsigned short* woT   = wqkvT + (size_t)2304 * 768;      // 768*768
  unsigned short* Qw    = woT   + (size_t)768 * 768;       // 4*8*2048*96 bf16
  unsigned short* Kw    = Qw    + (size_t)6291456;         // bf16
  _Float16*       Vw    = (_Float16*)(Kw + (size_t)6291456); // fp16 V^T
  unsigned short* Zw    = (unsigned short*)(Vw + (size_t)6291456); // 8192*768 bf16

  cvt_x_kernel<<<6144, 256, 0, stream>>>(x, xb);
  transpose_cvt_kernel<<<dim3(72, 24), dim3(32, 8), 0, stream>>>(Wqkv, wqkvT, 2304);
  transpose_cvt_kernel<<<dim3(24, 24), dim3(32, 8), 0, stream>>>(Wo, woT, 768);
  gemm_bt<0><<<dim3(18, 64), 256, 0, stream>>>(xb, wqkvT, Qw, Kw, Vw, nullptr, nullptr);
  flash_kernel<<<dim3(32, 8, 4), 256, 0, stream>>>(Qw, Kw, Vw, Zw);
  gemm_bt<1><<<dim3(6, 64), 256, 0, stream>>>(Zw, woT, nullptr, nullptr, nullptr, out, bo);
}

// Round 5
// 255.368 us; speedup vs baseline: 3.4894x; 1.0895x over previous
//
#include <hip/hip_runtime.h>

typedef __attribute__((ext_vector_type(8))) short short8;
typedef __attribute__((ext_vector_type(4))) float f32x4;
typedef __attribute__((ext_vector_type(4))) _Float16 half4;
typedef __attribute__((ext_vector_type(2))) __fp16 fp16x2;

#define B_SZ 4
#define NSEQ 2048
#define DIM  768
#define NH   8
#define DH   96

__device__ __forceinline__ unsigned short f2bf(float f) {
  unsigned int u = __float_as_uint(f);
  u += 0x7fffu + ((u >> 16) & 1u);   // RNE
  return (unsigned short)(u >> 16);
}

__device__ __forceinline__ float fexp2(float x) {
#if __has_builtin(__builtin_amdgcn_exp2f)
  return __builtin_amdgcn_exp2f(x);
#else
  return exp2f(x);
#endif
}

__device__ __forceinline__ void glds16(const void* g, void* l) {
  __builtin_amdgcn_global_load_lds((const __attribute__((address_space(1))) void*)g,
                                   (__attribute__((address_space(3))) void*)l, 16, 0, 0);
}

// ---------------- fp32 -> bf16 bulk convert (x) ----------------
__global__ __launch_bounds__(256) void cvt_x_kernel(const float* __restrict__ x,
                                                    unsigned short* __restrict__ xb) {
  int i = blockIdx.x * 256 + threadIdx.x;      // one float4 per thread
  float4 v = ((const float4*)x)[i];
  ushort4 o;
  o.x = f2bf(v.x); o.y = f2bf(v.y); o.z = f2bf(v.z); o.w = f2bf(v.w);
  ((ushort4*)xb)[i] = o;
}

// ---------------- transpose + convert weights: W[768][ncols] -> WT[ncols][768] bf16 ----------------
__global__ __launch_bounds__(256) void transpose_cvt_kernel(const float* __restrict__ W,
                                                            unsigned short* __restrict__ WT,
                                                            int ncols) {
  __shared__ float tile[32][33];
  int tx = threadIdx.x, ty = threadIdx.y;      // 32 x 8
  int c0 = blockIdx.x * 32;                    // along ncols
  int r0 = blockIdx.y * 32;                    // along 768
#pragma unroll
  for (int i = 0; i < 4; i++)
    tile[ty + i * 8][tx] = W[(size_t)(r0 + ty + i * 8) * ncols + c0 + tx];
  __syncthreads();
#pragma unroll
  for (int i = 0; i < 4; i++)
    WT[(size_t)(c0 + ty + i * 8) * 768 + r0 + tx] = f2bf(tile[tx][ty + i * 8]);
}

// ---------------- m97-style bf16 GEMM, A[M][768] @ Bt[N][768]^T, 128x128 tile ----------------
// EPI 0: scatter epilogue -> Q (scaled by dh^-0.5*log2e), K (bf16), V^T (fp16, 8B packed)
// EPI 1: +bias, fp32 out
template <int EPI>
__global__ __launch_bounds__(256) void gemm_bt(
    const unsigned short* __restrict__ A, const unsigned short* __restrict__ Bt,
    unsigned short* __restrict__ qo, unsigned short* __restrict__ ko,
    _Float16* __restrict__ vo, float* __restrict__ fo,
    const float* __restrict__ bias)
{
  __shared__ unsigned short As[128 * 32];
  __shared__ unsigned short Bs[128 * 32];
  const int t = threadIdx.x;
  const int w = t >> 6, lane = t & 63;
  const int l15 = lane & 15, qd = lane >> 4;
  const int m0 = blockIdx.y * 128, n0 = blockIdx.x * 128;
  const int wm = (w >> 1) * 64, wn = (w & 1) * 64;

  const int sr = lane >> 2;               // row within 16-row chunk
  const int sc = (lane & 3) * 8;          // col (shorts)
  const unsigned short* ga = A  + (size_t)(m0 + w * 16 + sr) * DIM + sc;
  const unsigned short* gb = Bt + (size_t)(n0 + w * 16 + sr) * DIM + sc;

  f32x4 acc[4][4] = {};

  for (int k0 = 0; k0 < DIM; k0 += 32) {
    glds16(ga + k0,            &As[w * 512]);
    glds16(ga + 64 * DIM + k0, &As[(4 + w) * 512]);
    glds16(gb + k0,            &Bs[w * 512]);
    glds16(gb + 64 * DIM + k0, &Bs[(4 + w) * 512]);
    __syncthreads();
    short8 af[4], bfr[4];
#pragma unroll
    for (int i = 0; i < 4; i++)
      af[i]  = *(const short8*)&As[(wm + i * 16 + l15) * 32 + qd * 8];
#pragma unroll
    for (int i = 0; i < 4; i++)
      bfr[i] = *(const short8*)&Bs[(wn + i * 16 + l15) * 32 + qd * 8];
#pragma unroll
    for (int mi = 0; mi < 4; mi++)
#pragma unroll
      for (int ni = 0; ni < 4; ni++)
        acc[mi][ni] = __builtin_amdgcn_mfma_f32_16x16x32_bf16(af[mi], bfr[ni], acc[mi][ni], 0, 0, 0);
    __syncthreads();
  }

#pragma unroll
  for (int mi = 0; mi < 4; mi++)
#pragma unroll
    for (int ni = 0; ni < 4; ni++) {
      int rowb = m0 + wm + mi * 16 + qd * 4;   // 4 consecutive rows per lane
      int col  = n0 + wn + ni * 16 + l15;
      if (EPI == 0) {
        int b = rowb >> 11, n = rowb & 2047;   // all 4 rows in same batch (rowb%2048<=2044)
        int s = col / DIM;                     // uniform per block (128 | 768)
        int rem = col - s * DIM;
        int hh = rem / DH;
        int c = rem - hh * DH;
        size_t bh = (size_t)(b * NH + hh);
        if (s == 2) {                          // V^T: 4 consecutive n at fixed c -> one 8B store
          half4 pk;
#pragma unroll
          for (int r = 0; r < 4; r++) pk[r] = (_Float16)acc[mi][ni][r];
          *(half4*)&vo[(bh * DH + c) * NSEQ + n] = pk;
        } else if (s == 0) {
#pragma unroll
          for (int r = 0; r < 4; r++)
            qo[(bh * NSEQ + n + r) * DH + c] = f2bf(acc[mi][ni][r] * 0.1472444679f); // dh^-0.5*log2e
        } else {
#pragma unroll
          for (int r = 0; r < 4; r++)
            ko[(bh * NSEQ + n + r) * DH + c] = f2bf(acc[mi][ni][r]);
        }
      } else {
#pragma unroll
        for (int r = 0; r < 4; r++)
          fo[(size_t)(rowb + r) * DIM + col] = acc[mi][ni][r] + bias[col];
      }
    }
}

// ---------------- flash attention v2.1: S^T formulation + XOR-swizzled K LDS ----------------
// One block per (b, h, 64-query tile). 4 waves, wave owns 16 q rows.
// S^T = K·Q^T (16x16x32 bf16): C/D frag (col=q, rows=keys) IS the B-operand frag of
// 16x16x16 f16 MFMA -> P feeds PV^T straight from registers. Row-sum via ones-A MFMA.
// K/Q LDS layout: 16B chunk (r,c) holds global chunk (r, c ^ ((r>>1)&3)) so that
// frag ds_read_b128 hits 8 distinct bank groups per 8-lane clique (conflict-free)
// while remaining global_load_lds-compatible (source-address permutation).
__global__ __launch_bounds__(256, 4) void flash_kernel(
    const unsigned short* __restrict__ Qb, const unsigned short* __restrict__ Kb,
    const _Float16* __restrict__ Vtb, unsigned short* __restrict__ Z)
{
  constexpr int VSTR = 72;                     // 144B rows: conflict-free staging/reads
  __shared__ unsigned short Ks[64 * 96];       // 12288 B (K tile; Q staging first)
  __shared__ _Float16 Vs[96 * VSTR];           // 13824 B (V^T tile [c][k])

  const int t = threadIdx.x, w = t >> 6, lane = t & 63;
  const int l15 = lane & 15, qd = lane >> 4;
  const int swz = (l15 >> 1) & 3;
  const int qt = blockIdx.x, h = blockIdx.y, b = blockIdx.z;
  const size_t bh = (size_t)(b * NH + h);
  const unsigned short* Qg = Qb + (bh * NSEQ + (size_t)qt * 64) * DH;
  const unsigned short* Kg = Kb + bh * NSEQ * DH;
  const _Float16*       Vg = Vtb + bh * (size_t)DH * NSEQ;

  // per-lane swizzled source offsets for K/Q staging (chunk L -> global chunk (r, c^((r>>1)&3)))
  int srcoff[3];
#pragma unroll
  for (int i = 0; i < 3; i++) {
    int L = w * 192 + i * 64 + lane;
    int r = L / 12, c = L - r * 12;
    srcoff[i] = r * 96 + ((c ^ ((r >> 1) & 3)) * 8);
  }

  // ---- stage Q tile (64x96 bf16) via global_load_lds, swizzled ----
#pragma unroll
  for (int i = 0; i < 3; i++)
    glds16(Qg + srcoff[i], &Ks[w * 1536 + i * 512]);
  __syncthreads();
  short8 qa[3];
#pragma unroll
  for (int ks = 0; ks < 3; ks++)
    qa[ks] = *(const short8*)&Ks[(w * 16 + l15) * 96 + ((ks * 4 + qd) ^ swz) * 8];

  f32x4 o[7] = {};                             // o[0..5]=O^T frags, o[6]=row-sum (ones trick)
  float mprev = -1e30f;                        // per-lane state: q = l15 (log2 domain)
  const half4 onef = {(_Float16)1.f, (_Float16)1.f, (_Float16)1.f, (_Float16)1.f};

  for (int kt = 0; kt < 32; kt++) {
    __syncthreads();                           // prev iter done reading Ks/Vs
    const unsigned short* Kt = Kg + (size_t)kt * 64 * DH;
#pragma unroll
    for (int i = 0; i < 3; i++)
      glds16(Kt + srcoff[i], &Ks[w * 1536 + i * 512]);
    const _Float16* Vt = Vg + kt * 64;
#pragma unroll
    for (int i = 0; i < 3; i++) {
      int idx = t + i * 256;
      int r = idx >> 3, oo = idx & 7;          // 96 rows x 8 float4
      *(float4*)&Vs[r * VSTR + oo * 8] = *(const float4*)(Vt + (size_t)r * NSEQ + oo * 8);
    }
    __syncthreads();

    // ---- S^T = K·Q^T : lane (qd,l15) gets keys fk*16+qd*4+r for q=l15 ----
    f32x4 s[4] = {};
#pragma unroll
    for (int ks = 0; ks < 3; ks++)
#pragma unroll
      for (int fk = 0; fk < 4; fk++) {
        short8 kf = *(const short8*)&Ks[(fk * 16 + l15) * 96 + ((ks * 4 + qd) ^ swz) * 8];
        s[fk] = __builtin_amdgcn_mfma_f32_16x16x32_bf16(kf, qa[ks], s[fk], 0, 0, 0);
      }

    // ---- online softmax, log2 domain, 1 scalar state per lane ----
    float mx = fmaxf(fmaxf(s[0][0], s[0][1]), fmaxf(s[0][2], s[0][3]));
#pragma unroll
    for (int fk = 1; fk < 4; fk++)
      mx = fmaxf(mx, fmaxf(fmaxf(s[fk][0], s[fk][1]), fmaxf(s[fk][2], s[fk][3])));
    mx = fmaxf(mx, __shfl_xor(mx, 16, 64));
    mx = fmaxf(mx, __shfl_xor(mx, 32, 64));
    float mnew = fmaxf(mprev, mx);
    float alpha = fexp2(mprev - mnew);
    mprev = mnew;

    half4 pf[4];
#pragma unroll
    for (int fk = 0; fk < 4; fk++) {
      union { fp16x2 h2[2]; half4 h4; } u;
      u.h2[0] = __builtin_amdgcn_cvt_pkrtz(fexp2(s[fk][0] - mnew), fexp2(s[fk][1] - mnew));
      u.h2[1] = __builtin_amdgcn_cvt_pkrtz(fexp2(s[fk][2] - mnew), fexp2(s[fk][3] - mnew));
      pf[fk] = u.h4;
    }
#pragma unroll
    for (int i = 0; i < 7; i++) o[i] = o[i] * alpha;

    // ---- O^T += V^T · P^T  (16x16x16 f16, P straight from registers) ----
#pragma unroll
    for (int fk = 0; fk < 4; fk++) {
#pragma unroll
      for (int fc = 0; fc < 6; fc++) {
        half4 vf = *(const half4*)&Vs[(fc * 16 + l15) * VSTR + fk * 16 + qd * 4];
        o[fc] = __builtin_amdgcn_mfma_f32_16x16x16f16(vf, pf[fk], o[fc], 0, 0, 0);
      }
      o[6] = __builtin_amdgcn_mfma_f32_16x16x16f16(onef, pf[fk], o[6], 0, 0, 0);
    }
  }

  // ---- epilogue: O/l, write Z with head-mixing reshape folded in ----
  float inv = 1.0f / o[6][0];                  // all rows of ones-frag equal the row-sum
  int q = qt * 64 + w * 16 + l15;
  size_t zbase = ((size_t)b * NSEQ + h * 256 + (q >> 3)) * DIM + (q & 7) * DH;
#pragma unroll
  for (int fc = 0; fc < 6; fc++)
#pragma unroll
    for (int r = 0; r < 4; r += 2) {
      unsigned int pkd = (unsigned int)f2bf(o[fc][r] * inv)
                       | ((unsigned int)f2bf(o[fc][r + 1] * inv) << 16);
      *(unsigned int*)&Z[zbase + fc * 16 + qd * 4 + r] = pkd;
    }
}

extern "C" void kernel_launch(void* const* d_in, const int* in_sizes, int n_in,
                              void* d_out, int out_size, void* d_ws, size_t ws_size,
                              hipStream_t stream)
{
  (void)in_sizes; (void)n_in; (void)out_size; (void)ws_size;
  const float* x    = (const float*)d_in[0];
  const float* Wqkv = (const float*)d_in[1];
  const float* Wo   = (const float*)d_in[2];
  const float* bo   = (const float*)d_in[3];
  float* out = (float*)d_out;

  unsigned short* ws    = (unsigned short*)d_ws;
  unsigned short* xb    = ws;                              // 8192*768
  unsigned short* wqkvT = xb    + (size_t)8192 * 768;      // 2304*768
  unsigned short* woT   = wqkvT + (size_t)2304 * 768;      // 768*768
  unsigned short* Qw    = woT   + (size_t)768 * 768;       // 4*8*2048*96 bf16
  unsigned short* Kw    = Qw    + (size_t)6291456;         // bf16
  _Float16*       Vw    = (_Float16*)(Kw + (size_t)6291456); // fp16 V^T
  unsigned short* Zw    = (unsigned short*)(Vw + (size_t)6291456); // 8192*768 bf16

  cvt_x_kernel<<<6144, 256, 0, stream>>>(x, xb);
  transpose_cvt_kernel<<<dim3(72, 24), dim3(32, 8), 0, stream>>>(Wqkv, wqkvT, 2304);
  transpose_cvt_kernel<<<dim3(24, 24), dim3(32, 8), 0, stream>>>(Wo, woT, 768);
  gemm_bt<0><<<dim3(18, 64), 256, 0, stream>>>(xb, wqkvT, Qw, Kw, Vw, nullptr, nullptr);
  flash_kernel<<<dim3(32, 8, 4), 256, 0, stream>>>(Qw, Kw, Vw, Zw);
  gemm_bt<1><<<dim3(6, 64), 256, 0, stream>>>(Zw, woT, nullptr, nullptr, nullptr, out, bo);
}

// Round 6
// 240.727 us; speedup vs baseline: 3.7016x; 1.0608x over previous
//
#include <hip/hip_runtime.h>

typedef __attribute__((ext_vector_type(8))) short short8;
typedef __attribute__((ext_vector_type(4))) float f32x4;
typedef __attribute__((ext_vector_type(4))) _Float16 half4;
typedef __attribute__((ext_vector_type(8))) _Float16 half8;
typedef __attribute__((ext_vector_type(2))) __fp16 fp16x2;

#define B_SZ 4
#define NSEQ 2048
#define DIM  768
#define NH   8
#define DH   96

__device__ __forceinline__ unsigned short f2bf(float f) {
  unsigned int u = __float_as_uint(f);
  u += 0x7fffu + ((u >> 16) & 1u);   // RNE
  return (unsigned short)(u >> 16);
}

__device__ __forceinline__ float fexp2(float x) {
#if __has_builtin(__builtin_amdgcn_exp2f)
  return __builtin_amdgcn_exp2f(x);
#else
  return exp2f(x);
#endif
}

__device__ __forceinline__ void glds16(const void* g, void* l) {
  __builtin_amdgcn_global_load_lds((const __attribute__((address_space(1))) void*)g,
                                   (__attribute__((address_space(3))) void*)l, 16, 0, 0);
}

// ---------------- fp32 -> bf16 bulk convert (x) ----------------
__global__ __launch_bounds__(256) void cvt_x_kernel(const float* __restrict__ x,
                                                    unsigned short* __restrict__ xb) {
  int i = blockIdx.x * 256 + threadIdx.x;      // one float4 per thread
  float4 v = ((const float4*)x)[i];
  ushort4 o;
  o.x = f2bf(v.x); o.y = f2bf(v.y); o.z = f2bf(v.z); o.w = f2bf(v.w);
  ((ushort4*)xb)[i] = o;
}

// ---------------- transpose + convert weights: W[768][ncols] -> WT[ncols][768] bf16 ----------------
__global__ __launch_bounds__(256) void transpose_cvt_kernel(const float* __restrict__ W,
                                                            unsigned short* __restrict__ WT,
                                                            int ncols) {
  __shared__ float tile[32][33];
  int tx = threadIdx.x, ty = threadIdx.y;      // 32 x 8
  int c0 = blockIdx.x * 32;                    // along ncols
  int r0 = blockIdx.y * 32;                    // along 768
#pragma unroll
  for (int i = 0; i < 4; i++)
    tile[ty + i * 8][tx] = W[(size_t)(r0 + ty + i * 8) * ncols + c0 + tx];
  __syncthreads();
#pragma unroll
  for (int i = 0; i < 4; i++)
    WT[(size_t)(c0 + ty + i * 8) * 768 + r0 + tx] = f2bf(tile[tx][ty + i * 8]);
}

// ---------------- m97-style bf16 GEMM, A[M][768] @ Bt[N][768]^T, 128x128 tile ----------------
// EPI 0: scatter epilogue -> Q (scaled by dh^-0.5*log2e), K (bf16), V^T (fp16, 8B packed)
// EPI 1: +bias, fp32 out
template <int EPI>
__global__ __launch_bounds__(256) void gemm_bt(
    const unsigned short* __restrict__ A, const unsigned short* __restrict__ Bt,
    unsigned short* __restrict__ qo, unsigned short* __restrict__ ko,
    _Float16* __restrict__ vo, float* __restrict__ fo,
    const float* __restrict__ bias)
{
  __shared__ unsigned short As[128 * 32];
  __shared__ unsigned short Bs[128 * 32];
  const int t = threadIdx.x;
  const int w = t >> 6, lane = t & 63;
  const int l15 = lane & 15, qd = lane >> 4;
  const int m0 = blockIdx.y * 128, n0 = blockIdx.x * 128;
  const int wm = (w >> 1) * 64, wn = (w & 1) * 64;

  const int sr = lane >> 2;               // row within 16-row chunk
  const int sc = (lane & 3) * 8;          // col (shorts)
  const unsigned short* ga = A  + (size_t)(m0 + w * 16 + sr) * DIM + sc;
  const unsigned short* gb = Bt + (size_t)(n0 + w * 16 + sr) * DIM + sc;

  f32x4 acc[4][4] = {};

  for (int k0 = 0; k0 < DIM; k0 += 32) {
    glds16(ga + k0,            &As[w * 512]);
    glds16(ga + 64 * DIM + k0, &As[(4 + w) * 512]);
    glds16(gb + k0,            &Bs[w * 512]);
    glds16(gb + 64 * DIM + k0, &Bs[(4 + w) * 512]);
    __syncthreads();
    short8 af[4], bfr[4];
#pragma unroll
    for (int i = 0; i < 4; i++)
      af[i]  = *(const short8*)&As[(wm + i * 16 + l15) * 32 + qd * 8];
#pragma unroll
    for (int i = 0; i < 4; i++)
      bfr[i] = *(const short8*)&Bs[(wn + i * 16 + l15) * 32 + qd * 8];
#pragma unroll
    for (int mi = 0; mi < 4; mi++)
#pragma unroll
      for (int ni = 0; ni < 4; ni++)
        acc[mi][ni] = __builtin_amdgcn_mfma_f32_16x16x32_bf16(af[mi], bfr[ni], acc[mi][ni], 0, 0, 0);
    __syncthreads();
  }

#pragma unroll
  for (int mi = 0; mi < 4; mi++)
#pragma unroll
    for (int ni = 0; ni < 4; ni++) {
      int rowb = m0 + wm + mi * 16 + qd * 4;   // 4 consecutive rows per lane
      int col  = n0 + wn + ni * 16 + l15;
      if (EPI == 0) {
        int b = rowb >> 11, n = rowb & 2047;   // all 4 rows in same batch (rowb%2048<=2044)
        int s = col / DIM;                     // uniform per block (128 | 768)
        int rem = col - s * DIM;
        int hh = rem / DH;
        int c = rem - hh * DH;
        size_t bh = (size_t)(b * NH + hh);
        if (s == 2) {                          // V^T: 4 consecutive n at fixed c -> one 8B store
          half4 pk;
#pragma unroll
          for (int r = 0; r < 4; r++) pk[r] = (_Float16)acc[mi][ni][r];
          *(half4*)&vo[(bh * DH + c) * NSEQ + n] = pk;
        } else if (s == 0) {
#pragma unroll
          for (int r = 0; r < 4; r++)
            qo[(bh * NSEQ + n + r) * DH + c] = f2bf(acc[mi][ni][r] * 0.1472444679f); // dh^-0.5*log2e
        } else {
#pragma unroll
          for (int r = 0; r < 4; r++)
            ko[(bh * NSEQ + n + r) * DH + c] = f2bf(acc[mi][ni][r]);
        }
      } else {
#pragma unroll
        for (int r = 0; r < 4; r++)
          fo[(size_t)(rowb + r) * DIM + col] = acc[mi][ni][r] + bias[col];
      }
    }
}

// ---------------- flash attention v3: key-permuted S^T + K=32 PV, full-DMA staging --------
// One block per (b, h, 64-query tile). 4 waves, wave owns 16 (scattered) q's.
// K/Q staged with ROW PERMUTATION keyof(r)=32(fk&1)+4(fk>>1)+8(m>>2)+(m&3) (r=fk*16+m)
// so a lane's S^T C-frags s[fk][r] hold keys 32(fk&1)+4(fk>>1)+8qd+r. Concatenating
// (pf[p], pf[p+2]) yields the B-operand (k=qd*8+j) of mfma_f32_16x16x32_f16 for keys
// 32p+qd*8+j -> PV runs at full K=32 straight from registers. Row-sum via ones-A MFMA.
// Col XOR-swizzles keep all LDS frag reads bank-conflict-free; V staged by global_load_lds
// into unpadded Vs[96][64] with chunk swizzle c^(r&7).
__global__ __launch_bounds__(256, 4) void flash_kernel(
    const unsigned short* __restrict__ Qb, const unsigned short* __restrict__ Kb,
    const _Float16* __restrict__ Vtb, unsigned short* __restrict__ Z)
{
  __shared__ unsigned short Ks[64 * 96];      // 12288 B: row-permuted, col-swizzled K (Q first)
  __shared__ _Float16 Vs[96 * 64];            // 12288 B: V^T tile, chunk-swizzled

  const int t = threadIdx.x, w = t >> 6, lane = t & 63;
  const int l15 = lane & 15, qd = lane >> 4;
  const int swz = (l15 >> 1) & 3;
  const int vswz = l15 & 7;
  const int qt = blockIdx.x, h = blockIdx.y, b = blockIdx.z;
  const size_t bh = (size_t)(b * NH + h);
  const unsigned short* Qg = Qb + (bh * NSEQ + (size_t)qt * 64) * DH;
  const unsigned short* Kg = Kb + bh * NSEQ * DH;
  const _Float16*       Vg = Vtb + bh * (size_t)DH * NSEQ;

  // K/Q staging: LDS chunk L=(w*192+i*64+lane) -> row r=L/12, col c=L%12;
  // row r holds global row keyof(r), col holds logical chunk c^((r>>1)&3).
  int koff[3];
#pragma unroll
  for (int i = 0; i < 3; i++) {
    int L = w * 192 + i * 64 + lane;
    int r = L / 12, c = L - r * 12;
    int fk = r >> 4, m = r & 15;
    int key = 32 * (fk & 1) + 4 * (fk >> 1) + 8 * (m >> 2) + (m & 3);
    koff[i] = key * 96 + ((c ^ ((r >> 1) & 3)) * 8);
  }
  // V staging: chunk L=(i*256+t) -> dh-row r=L>>3, col c=L&7; holds logical chunk c^(r&7).
  int voff[3];
#pragma unroll
  for (int i = 0; i < 3; i++) {
    int L = i * 256 + t;
    int r = L >> 3, c = L & 7;
    voff[i] = r * NSEQ + ((c ^ (r & 7)) * 8);
  }

  // ---- stage Q tile (row-permuted) ----
#pragma unroll
  for (int i = 0; i < 3; i++)
    glds16(Qg + koff[i], &Ks[w * 1536 + i * 512]);
  __syncthreads();
  short8 qa[3];
#pragma unroll
  for (int ks = 0; ks < 3; ks++)
    qa[ks] = *(const short8*)&Ks[(w * 16 + l15) * 96 + ((ks * 4 + qd) ^ swz) * 8];

  f32x4 o[7] = {};                             // o[0..5]=O^T frags, o[6]=row-sum (ones trick)
  float mprev = -1e30f;                        // per-lane state (log2 domain)
  const half8 onef = {(_Float16)1.f, (_Float16)1.f, (_Float16)1.f, (_Float16)1.f,
                      (_Float16)1.f, (_Float16)1.f, (_Float16)1.f, (_Float16)1.f};

  for (int kt = 0; kt < 32; kt++) {
    __syncthreads();                           // prev iter done reading Ks/Vs
    const unsigned short* Kt = Kg + (size_t)kt * 64 * DH;
#pragma unroll
    for (int i = 0; i < 3; i++)
      glds16(Kt + koff[i], &Ks[w * 1536 + i * 512]);
    const _Float16* Vt = Vg + kt * 64;
#pragma unroll
    for (int i = 0; i < 3; i++)
      glds16(Vt + voff[i], &Vs[(i * 256 + w * 64) * 8]);
    __syncthreads();

    // ---- S^T = K·Q^T : s[fk][r] = S(key=32(fk&1)+4(fk>>1)+8qd+r, q=qof(l15)) ----
    f32x4 s[4] = {};
#pragma unroll
    for (int ks = 0; ks < 3; ks++)
#pragma unroll
      for (int fk = 0; fk < 4; fk++) {
        short8 kf = *(const short8*)&Ks[(fk * 16 + l15) * 96 + ((ks * 4 + qd) ^ swz) * 8];
        s[fk] = __builtin_amdgcn_mfma_f32_16x16x32_bf16(kf, qa[ks], s[fk], 0, 0, 0);
      }

    // ---- online softmax, log2 domain ----
    float mx = fmaxf(fmaxf(s[0][0], s[0][1]), fmaxf(s[0][2], s[0][3]));
#pragma unroll
    for (int fk = 1; fk < 4; fk++)
      mx = fmaxf(mx, fmaxf(fmaxf(s[fk][0], s[fk][1]), fmaxf(s[fk][2], s[fk][3])));
    mx = fmaxf(mx, __shfl_xor(mx, 16, 64));
    mx = fmaxf(mx, __shfl_xor(mx, 32, 64));
    float mnew = fmaxf(mprev, mx);
    float alpha = fexp2(mprev - mnew);
    mprev = mnew;

    half4 pf[4];
#pragma unroll
    for (int fk = 0; fk < 4; fk++) {
      union { fp16x2 h2[2]; half4 h4; } u;
      u.h2[0] = __builtin_amdgcn_cvt_pkrtz(fexp2(s[fk][0] - mnew), fexp2(s[fk][1] - mnew));
      u.h2[1] = __builtin_amdgcn_cvt_pkrtz(fexp2(s[fk][2] - mnew), fexp2(s[fk][3] - mnew));
      pf[fk] = u.h4;
    }
#pragma unroll
    for (int i = 0; i < 7; i++) o[i] = o[i] * alpha;

    // ---- O^T += V^T · P^T  (16x16x32 f16, keys p*32..p*32+31 per MFMA) ----
#pragma unroll
    for (int p = 0; p < 2; p++) {
      union { half4 h4[2]; half8 h8; } bu;
      bu.h4[0] = pf[p]; bu.h4[1] = pf[p + 2];
#pragma unroll
      for (int fc = 0; fc < 6; fc++) {
        half8 vf = *(const half8*)&Vs[(fc * 16 + l15) * 64 + ((p * 4 + qd) ^ vswz) * 8];
        o[fc] = __builtin_amdgcn_mfma_f32_16x16x32_f16(vf, bu.h8, o[fc], 0, 0, 0);
      }
      o[6] = __builtin_amdgcn_mfma_f32_16x16x32_f16(onef, bu.h8, o[6], 0, 0, 0);
    }
  }

  // ---- epilogue: O/l, write Z with head-mixing reshape folded in ----
  float inv = 1.0f / o[6][0];                  // all rows of ones-frag equal the row-sum
  int qloc = 32 * (w & 1) + 4 * (w >> 1) + 8 * (l15 >> 2) + (l15 & 3);  // keyof(w*16+l15)
  int q = qt * 64 + qloc;
  size_t zbase = ((size_t)b * NSEQ + h * 256 + (q >> 3)) * DIM + (q & 7) * DH;
#pragma unroll
  for (int fc = 0; fc < 6; fc++)
#pragma unroll
    for (int r = 0; r < 4; r += 2) {
      unsigned int pkd = (unsigned int)f2bf(o[fc][r] * inv)
                       | ((unsigned int)f2bf(o[fc][r + 1] * inv) << 16);
      *(unsigned int*)&Z[zbase + fc * 16 + qd * 4 + r] = pkd;
    }
}

extern "C" void kernel_launch(void* const* d_in, const int* in_sizes, int n_in,
                              void* d_out, int out_size, void* d_ws, size_t ws_size,
                              hipStream_t stream)
{
  (void)in_sizes; (void)n_in; (void)out_size; (void)ws_size;
  const float* x    = (const float*)d_in[0];
  const float* Wqkv = (const float*)d_in[1];
  const float* Wo   = (const float*)d_in[2];
  const float* bo   = (const float*)d_in[3];
  float* out = (float*)d_out;

  unsigned short* ws    = (unsigned short*)d_ws;
  unsigned short* xb    = ws;                              // 8192*768
  unsigned short* wqkvT = xb    + (size_t)8192 * 768;      // 2304*768
  unsigned short* woT   = wqkvT + (size_t)2304 * 768;      // 768*768
  unsigned short* Qw    = woT   + (size_t)768 * 768;       // 4*8*2048*96 bf16
  unsigned short* Kw    = Qw    + (size_t)6291456;         // bf16
  _Float16*       Vw    = (_Float16*)(Kw + (size_t)6291456); // fp16 V^T
  unsigned short* Zw    = (unsigned short*)(Vw + (size_t)6291456); // 8192*768 bf16

  cvt_x_kernel<<<6144, 256, 0, stream>>>(x, xb);
  transpose_cvt_kernel<<<dim3(72, 24), dim3(32, 8), 0, stream>>>(Wqkv, wqkvT, 2304);
  transpose_cvt_kernel<<<dim3(24, 24), dim3(32, 8), 0, stream>>>(Wo, woT, 768);
  gemm_bt<0><<<dim3(18, 64), 256, 0, stream>>>(xb, wqkvT, Qw, Kw, Vw, nullptr, nullptr);
  flash_kernel<<<dim3(32, 8, 4), 256, 0, stream>>>(Qw, Kw, Vw, Zw);
  gemm_bt<1><<<dim3(6, 64), 256, 0, stream>>>(Zw, woT, nullptr, nullptr, nullptr, out, bo);
}

// Round 7
// 226.873 us; speedup vs baseline: 3.9277x; 1.0611x over previous
//
#include <hip/hip_runtime.h>

typedef __attribute__((ext_vector_type(8))) short short8;
typedef __attribute__((ext_vector_type(4))) float f32x4;
typedef __attribute__((ext_vector_type(4))) _Float16 half4;
typedef __attribute__((ext_vector_type(8))) _Float16 half8;
typedef __attribute__((ext_vector_type(2))) __fp16 fp16x2;

#define B_SZ 4
#define NSEQ 2048
#define DIM  768
#define NH   8
#define DH   96

__device__ __forceinline__ unsigned short f2bf(float f) {
  unsigned int u = __float_as_uint(f);
  u += 0x7fffu + ((u >> 16) & 1u);   // RNE
  return (unsigned short)(u >> 16);
}

__device__ __forceinline__ float fexp2(float x) {
#if __has_builtin(__builtin_amdgcn_exp2f)
  return __builtin_amdgcn_exp2f(x);
#else
  return exp2f(x);
#endif
}

__device__ __forceinline__ void glds16(const void* g, void* l) {
  __builtin_amdgcn_global_load_lds((const __attribute__((address_space(1))) void*)g,
                                   (__attribute__((address_space(3))) void*)l, 16, 0, 0);
}

// ---------------- fp32 -> bf16 bulk convert (x) ----------------
__global__ __launch_bounds__(256) void cvt_x_kernel(const float* __restrict__ x,
                                                    unsigned short* __restrict__ xb) {
  int i = blockIdx.x * 256 + threadIdx.x;      // one float4 per thread
  float4 v = ((const float4*)x)[i];
  ushort4 o;
  o.x = f2bf(v.x); o.y = f2bf(v.y); o.z = f2bf(v.z); o.w = f2bf(v.w);
  ((ushort4*)xb)[i] = o;
}

// ---------------- transpose + convert weights: W[768][ncols] -> WT[ncols][768] bf16 ----------------
__global__ __launch_bounds__(256) void transpose_cvt_kernel(const float* __restrict__ W,
                                                            unsigned short* __restrict__ WT,
                                                            int ncols) {
  __shared__ float tile[32][33];
  int tx = threadIdx.x, ty = threadIdx.y;      // 32 x 8
  int c0 = blockIdx.x * 32;                    // along ncols
  int r0 = blockIdx.y * 32;                    // along 768
#pragma unroll
  for (int i = 0; i < 4; i++)
    tile[ty + i * 8][tx] = W[(size_t)(r0 + ty + i * 8) * ncols + c0 + tx];
  __syncthreads();
#pragma unroll
  for (int i = 0; i < 4; i++)
    WT[(size_t)(c0 + ty + i * 8) * 768 + r0 + tx] = f2bf(tile[tx][ty + i * 8]);
}

// ---------------- bf16 GEMM, A[M][768] @ Bt[N][768]^T, 128x128 tile, XOR-swizzled LDS ----
// LDS chunk (row, c) holds global 16B-chunk (row, c ^ ((row>>1)&3)) so frag ds_read_b128
// spreads each 8-lane clique over all 4 chunk positions (2 lanes/bank = free).
// EPI 0: scatter epilogue -> Q (scaled by dh^-0.5*log2e), K (bf16), V^T (fp16, 8B packed)
// EPI 1: +bias, fp32 out
template <int EPI>
__global__ __launch_bounds__(256) void gemm_bt(
    const unsigned short* __restrict__ A, const unsigned short* __restrict__ Bt,
    unsigned short* __restrict__ qo, unsigned short* __restrict__ ko,
    _Float16* __restrict__ vo, float* __restrict__ fo,
    const float* __restrict__ bias)
{
  __shared__ unsigned short As[128 * 32];
  __shared__ unsigned short Bs[128 * 32];
  const int t = threadIdx.x;
  const int w = t >> 6, lane = t & 63;
  const int l15 = lane & 15, qd = lane >> 4;
  const int asw = (l15 >> 1) & 3;          // read-side chunk XOR
  const int m0 = blockIdx.y * 128, n0 = blockIdx.x * 128;
  const int wm = (w >> 1) * 64, wn = (w & 1) * 64;

  const int sr = lane >> 2;                // row within 16-row chunk
  const int sc = ((lane & 3) ^ ((sr >> 1) & 3)) * 8;   // swizzled source chunk
  const unsigned short* ga = A  + (size_t)(m0 + w * 16 + sr) * DIM + sc;
  const unsigned short* gb = Bt + (size_t)(n0 + w * 16 + sr) * DIM + sc;

  f32x4 acc[4][4] = {};

  for (int k0 = 0; k0 < DIM; k0 += 32) {
    glds16(ga + k0,            &As[w * 512]);
    glds16(ga + 64 * DIM + k0, &As[(4 + w) * 512]);
    glds16(gb + k0,            &Bs[w * 512]);
    glds16(gb + 64 * DIM + k0, &Bs[(4 + w) * 512]);
    __syncthreads();
    short8 af[4], bfr[4];
#pragma unroll
    for (int i = 0; i < 4; i++)
      af[i]  = *(const short8*)&As[(wm + i * 16 + l15) * 32 + (qd ^ asw) * 8];
#pragma unroll
    for (int i = 0; i < 4; i++)
      bfr[i] = *(const short8*)&Bs[(wn + i * 16 + l15) * 32 + (qd ^ asw) * 8];
#pragma unroll
    for (int mi = 0; mi < 4; mi++)
#pragma unroll
      for (int ni = 0; ni < 4; ni++)
        acc[mi][ni] = __builtin_amdgcn_mfma_f32_16x16x32_bf16(af[mi], bfr[ni], acc[mi][ni], 0, 0, 0);
    __syncthreads();
  }

#pragma unroll
  for (int mi = 0; mi < 4; mi++)
#pragma unroll
    for (int ni = 0; ni < 4; ni++) {
      int rowb = m0 + wm + mi * 16 + qd * 4;   // 4 consecutive rows per lane
      int col  = n0 + wn + ni * 16 + l15;
      if (EPI == 0) {
        int b = rowb >> 11, n = rowb & 2047;
        int s = col / DIM;                     // uniform per block (128 | 768)
        int rem = col - s * DIM;
        int hh = rem / DH;
        int c = rem - hh * DH;
        size_t bh = (size_t)(b * NH + hh);
        if (s == 2) {                          // V^T: 4 consecutive n at fixed c -> one 8B store
          half4 pk;
#pragma unroll
          for (int r = 0; r < 4; r++) pk[r] = (_Float16)acc[mi][ni][r];
          *(half4*)&vo[(bh * DH + c) * NSEQ + n] = pk;
        } else if (s == 0) {
#pragma unroll
          for (int r = 0; r < 4; r++)
            qo[(bh * NSEQ + n + r) * DH + c] = f2bf(acc[mi][ni][r] * 0.1472444679f); // dh^-0.5*log2e
        } else {
#pragma unroll
          for (int r = 0; r < 4; r++)
            ko[(bh * NSEQ + n + r) * DH + c] = f2bf(acc[mi][ni][r]);
        }
      } else {
#pragma unroll
        for (int r = 0; r < 4; r++)
          fo[(size_t)(rowb + r) * DIM + col] = acc[mi][ni][r] + bias[col];
      }
    }
}

// ---------------- flash attention v4: 128-query tiles, key-permuted S^T + K=32 PV ---------
// One block per (b, h, 128-query tile): 512 blocks = 2/CU, Q reuse doubled vs v3
// (halves K/V staging traffic, HBM fetch, and barrier events per CU).
// Q staged once (24.6 KB, overlapping the K+V loop buffers via union), identity rows.
// K staged with row permutation keyof(r)=32(fk&1)+4(fk>>1)+8(m>>2)+(m&3) so a lane's
// S^T C-frags concatenate ((pf[p],pf[p+2])) into the K=32 f16 B-operand. Row-sum via
// ones-A MFMA. All LDS frag reads XOR-swizzled conflict-free.
__global__ __launch_bounds__(256, 2) void flash_kernel(
    const unsigned short* __restrict__ Qb, const unsigned short* __restrict__ Kb,
    const _Float16* __restrict__ Vtb, unsigned short* __restrict__ Z)
{
  __shared__ unsigned char smem[24576];
  unsigned short* Qs = (unsigned short*)smem;         // 128x96 bf16 (staging phase)
  unsigned short* Ks = (unsigned short*)smem;         // 64x96 bf16 (loop phase)
  _Float16*       Vs = (_Float16*)(smem + 12288);     // 96x64 fp16 (loop phase)

  const int t = threadIdx.x, w = t >> 6, lane = t & 63;
  const int l15 = lane & 15, qd = lane >> 4;
  const int swz = (l15 >> 1) & 3;
  const int vswz = l15 & 7;
  const int qt = blockIdx.x, h = blockIdx.y, b = blockIdx.z;
  const size_t bh = (size_t)(b * NH + h);
  const unsigned short* Qg = Qb + (bh * NSEQ + (size_t)qt * 128) * DH;
  const unsigned short* Kg = Kb + bh * NSEQ * DH;
  const _Float16*       Vg = Vtb + bh * (size_t)DH * NSEQ;

  // Q staging: chunk L=(i*256+t) -> row r=L/12 (identity), col c holds logical c^((r>>1)&3)
  int qoff[6];
#pragma unroll
  for (int i = 0; i < 6; i++) {
    int L = i * 256 + t;
    int r = L / 12, c = L - r * 12;
    qoff[i] = r * 96 + ((c ^ ((r >> 1) & 3)) * 8);
  }
  // K staging: row r holds global key keyof(r), col swizzled
  int koff[3];
#pragma unroll
  for (int i = 0; i < 3; i++) {
    int L = w * 192 + i * 64 + lane;
    int r = L / 12, c = L - r * 12;
    int fk = r >> 4, m = r & 15;
    int key = 32 * (fk & 1) + 4 * (fk >> 1) + 8 * (m >> 2) + (m & 3);
    koff[i] = key * 96 + ((c ^ ((r >> 1) & 3)) * 8);
  }
  // V staging: chunk L=(i*256+t) -> dh-row r=L>>3, col c holds logical c^(r&7)
  int voff[3];
#pragma unroll
  for (int i = 0; i < 3; i++) {
    int L = i * 256 + t;
    int r = L >> 3, c = L & 7;
    voff[i] = r * NSEQ + ((c ^ (r & 7)) * 8);
  }

  // ---- stage Q tile (128x96), pull register-resident fragments for both q-groups ----
#pragma unroll
  for (int i = 0; i < 6; i++)
    glds16(Qg + qoff[i], &Qs[i * 2048 + w * 512]);
  __syncthreads();
  short8 qa[2][3];
#pragma unroll
  for (int fq = 0; fq < 2; fq++)
#pragma unroll
    for (int ks = 0; ks < 3; ks++)
      qa[fq][ks] = *(const short8*)&Qs[(w * 32 + fq * 16 + l15) * 96 + ((ks * 4 + qd) ^ swz) * 8];

  f32x4 o[2][7] = {};                          // [fq][0..5]=O^T frags, [fq][6]=row-sum
  float mprev[2] = {-1e30f, -1e30f};           // per-lane, log2 domain
  const half8 onef = {(_Float16)1.f, (_Float16)1.f, (_Float16)1.f, (_Float16)1.f,
                      (_Float16)1.f, (_Float16)1.f, (_Float16)1.f, (_Float16)1.f};

  for (int kt = 0; kt < 32; kt++) {
    __syncthreads();                           // prev iter done reading Ks/Vs (and Qs frags)
    const unsigned short* Kt = Kg + (size_t)kt * 64 * DH;
#pragma unroll
    for (int i = 0; i < 3; i++)
      glds16(Kt + koff[i], &Ks[w * 1536 + i * 512]);
    const _Float16* Vt = Vg + kt * 64;
#pragma unroll
    for (int i = 0; i < 3; i++)
      glds16(Vt + voff[i], &Vs[(i * 256 + w * 64) * 8]);
    __syncthreads();

    // ---- S^T = K·Q^T for both q-groups: s[fq][fk][r] = key 32(fk&1)+4(fk>>1)+8qd+r ----
    f32x4 s[2][4] = {};
#pragma unroll
    for (int ks = 0; ks < 3; ks++)
#pragma unroll
      for (int fk = 0; fk < 4; fk++) {
        short8 kf = *(const short8*)&Ks[(fk * 16 + l15) * 96 + ((ks * 4 + qd) ^ swz) * 8];
        s[0][fk] = __builtin_amdgcn_mfma_f32_16x16x32_bf16(kf, qa[0][ks], s[0][fk], 0, 0, 0);
        s[1][fk] = __builtin_amdgcn_mfma_f32_16x16x32_bf16(kf, qa[1][ks], s[1][fk], 0, 0, 0);
      }

#pragma unroll
    for (int fq = 0; fq < 2; fq++) {
      // ---- online softmax, log2 domain ----
      float mx = fmaxf(fmaxf(s[fq][0][0], s[fq][0][1]), fmaxf(s[fq][0][2], s[fq][0][3]));
#pragma unroll
      for (int fk = 1; fk < 4; fk++)
        mx = fmaxf(mx, fmaxf(fmaxf(s[fq][fk][0], s[fq][fk][1]), fmaxf(s[fq][fk][2], s[fq][fk][3])));
      mx = fmaxf(mx, __shfl_xor(mx, 16, 64));
      mx = fmaxf(mx, __shfl_xor(mx, 32, 64));
      float mnew = fmaxf(mprev[fq], mx);
      float alpha = fexp2(mprev[fq] - mnew);
      mprev[fq] = mnew;

      half4 pf[4];
#pragma unroll
      for (int fk = 0; fk < 4; fk++) {
        union { fp16x2 h2[2]; half4 h4; } u;
        u.h2[0] = __builtin_amdgcn_cvt_pkrtz(fexp2(s[fq][fk][0] - mnew), fexp2(s[fq][fk][1] - mnew));
        u.h2[1] = __builtin_amdgcn_cvt_pkrtz(fexp2(s[fq][fk][2] - mnew), fexp2(s[fq][fk][3] - mnew));
        pf[fk] = u.h4;
      }
#pragma unroll
      for (int i = 0; i < 7; i++) o[fq][i] = o[fq][i] * alpha;

      // ---- O^T += V^T · P^T  (16x16x32 f16, keys p*32..p*32+31 per MFMA) ----
#pragma unroll
      for (int p = 0; p < 2; p++) {
        union { half4 h4[2]; half8 h8; } bu;
        bu.h4[0] = pf[p]; bu.h4[1] = pf[p + 2];
#pragma unroll
        for (int fc = 0; fc < 6; fc++) {
          half8 vf = *(const half8*)&Vs[(fc * 16 + l15) * 64 + ((p * 4 + qd) ^ vswz) * 8];
          o[fq][fc] = __builtin_amdgcn_mfma_f32_16x16x32_f16(vf, bu.h8, o[fq][fc], 0, 0, 0);
        }
        o[fq][6] = __builtin_amdgcn_mfma_f32_16x16x32_f16(onef, bu.h8, o[fq][6], 0, 0, 0);
      }
    }
  }

  // ---- epilogue: O/l, write Z with head-mixing reshape folded in ----
#pragma unroll
  for (int fq = 0; fq < 2; fq++) {
    float inv = 1.0f / o[fq][6][0];            // all rows of ones-frag equal the row-sum
    int q = qt * 128 + w * 32 + fq * 16 + l15;
    size_t zbase = ((size_t)b * NSEQ + h * 256 + (q >> 3)) * DIM + (q & 7) * DH;
#pragma unroll
    for (int fc = 0; fc < 6; fc++)
#pragma unroll
      for (int r = 0; r < 4; r += 2) {
        unsigned int pkd = (unsigned int)f2bf(o[fq][fc][r] * inv)
                         | ((unsigned int)f2bf(o[fq][fc][r + 1] * inv) << 16);
        *(unsigned int*)&Z[zbase + fc * 16 + qd * 4 + r] = pkd;
      }
  }
}

extern "C" void kernel_launch(void* const* d_in, const int* in_sizes, int n_in,
                              void* d_out, int out_size, void* d_ws, size_t ws_size,
                              hipStream_t stream)
{
  (void)in_sizes; (void)n_in; (void)out_size; (void)ws_size;
  const float* x    = (const float*)d_in[0];
  const float* Wqkv = (const float*)d_in[1];
  const float* Wo   = (const float*)d_in[2];
  const float* bo   = (const float*)d_in[3];
  float* out = (float*)d_out;

  unsigned short* ws    = (unsigned short*)d_ws;
  unsigned short* xb    = ws;                              // 8192*768
  unsigned short* wqkvT = xb    + (size_t)8192 * 768;      // 2304*768
  unsigned short* woT   = wqkvT + (size_t)2304 * 768;      // 768*768
  unsigned short* Qw    = woT   + (size_t)768 * 768;       // 4*8*2048*96 bf16
  unsigned short* Kw    = Qw    + (size_t)6291456;         // bf16
  _Float16*       Vw    = (_Float16*)(Kw + (size_t)6291456); // fp16 V^T
  unsigned short* Zw    = (unsigned short*)(Vw + (size_t)6291456); // 8192*768 bf16

  cvt_x_kernel<<<6144, 256, 0, stream>>>(x, xb);
  transpose_cvt_kernel<<<dim3(72, 24), dim3(32, 8), 0, stream>>>(Wqkv, wqkvT, 2304);
  transpose_cvt_kernel<<<dim3(24, 24), dim3(32, 8), 0, stream>>>(Wo, woT, 768);
  gemm_bt<0><<<dim3(18, 64), 256, 0, stream>>>(xb, wqkvT, Qw, Kw, Vw, nullptr, nullptr);
  flash_kernel<<<dim3(16, 8, 4), 256, 0, stream>>>(Qw, Kw, Vw, Zw);
  gemm_bt<1><<<dim3(6, 64), 256, 0, stream>>>(Zw, woT, nullptr, nullptr, nullptr, out, bo);
}

// Round 8
// 223.729 us; speedup vs baseline: 3.9829x; 1.0141x over previous
//
#include <hip/hip_runtime.h>

typedef __attribute__((ext_vector_type(8))) short short8;
typedef __attribute__((ext_vector_type(4))) float f32x4;
typedef __attribute__((ext_vector_type(4))) _Float16 half4;
typedef __attribute__((ext_vector_type(8))) _Float16 half8;
typedef __attribute__((ext_vector_type(2))) __fp16 fp16x2;

#define B_SZ 4
#define NSEQ 2048
#define DIM  768
#define NH   8
#define DH   96

__device__ __forceinline__ unsigned short f2bf(float f) {
  unsigned int u = __float_as_uint(f);
  u += 0x7fffu + ((u >> 16) & 1u);   // RNE
  return (unsigned short)(u >> 16);
}

__device__ __forceinline__ float fexp2(float x) {
#if __has_builtin(__builtin_amdgcn_exp2f)
  return __builtin_amdgcn_exp2f(x);
#else
  return exp2f(x);
#endif
}

__device__ __forceinline__ void glds16(const void* g, void* l) {
  __builtin_amdgcn_global_load_lds((const __attribute__((address_space(1))) void*)g,
                                   (__attribute__((address_space(3))) void*)l, 16, 0, 0);
}

// ---------------- fused prep: x->bf16 convert + both weight transposes ----------------
// blocks [0,6144): cvt x (one float4/thread); [6144,7872): W_qkv^T; [7872,8448): W_o^T
__global__ __launch_bounds__(256) void prep_kernel(
    const float* __restrict__ x, unsigned short* __restrict__ xb,
    const float* __restrict__ Wqkv, unsigned short* __restrict__ wqkvT,
    const float* __restrict__ Wo, unsigned short* __restrict__ woT)
{
  int blk = blockIdx.x;
  if (blk < 6144) {
    int i = blk * 256 + threadIdx.x;
    float4 v = ((const float4*)x)[i];
    ushort4 o;
    o.x = f2bf(v.x); o.y = f2bf(v.y); o.z = f2bf(v.z); o.w = f2bf(v.w);
    ((ushort4*)xb)[i] = o;
    return;
  }
  __shared__ float tile[32][33];
  const float* W; unsigned short* WT; int ncols, bx, by;
  if (blk < 7872) { int r = blk - 6144; W = Wqkv; WT = wqkvT; ncols = 2304; bx = r % 72; by = r / 72; }
  else            { int r = blk - 7872; W = Wo;   WT = woT;   ncols = 768;  bx = r % 24; by = r / 24; }
  int tx = threadIdx.x & 31, ty = threadIdx.x >> 5;      // 32 x 8
  int c0 = bx * 32, r0 = by * 32;
#pragma unroll
  for (int i = 0; i < 4; i++)
    tile[ty + i * 8][tx] = W[(size_t)(r0 + ty + i * 8) * ncols + c0 + tx];
  __syncthreads();
#pragma unroll
  for (int i = 0; i < 4; i++)
    WT[(size_t)(c0 + ty + i * 8) * 768 + r0 + tx] = f2bf(tile[tx][ty + i * 8]);
}

// ---------------- bf16 GEMM, A[M][768] @ Bt[N][768]^T, 128x128 tile, XOR-swizzled LDS ----
// LDS chunk (row, c) holds global 16B-chunk (row, c ^ ((row>>1)&3)) so frag ds_read_b128
// spreads each 8-lane clique over all 4 chunk positions (2 lanes/bank = free).
// EPI 0: scatter epilogue -> Q (scaled by dh^-0.5*log2e), K (bf16), V^T (fp16, 8B packed)
// EPI 1: +bias, fp32 out
template <int EPI>
__global__ __launch_bounds__(256) void gemm_bt(
    const unsigned short* __restrict__ A, const unsigned short* __restrict__ Bt,
    unsigned short* __restrict__ qo, unsigned short* __restrict__ ko,
    _Float16* __restrict__ vo, float* __restrict__ fo,
    const float* __restrict__ bias)
{
  __shared__ unsigned short As[128 * 32];
  __shared__ unsigned short Bs[128 * 32];
  const int t = threadIdx.x;
  const int w = t >> 6, lane = t & 63;
  const int l15 = lane & 15, qd = lane >> 4;
  const int asw = (l15 >> 1) & 3;          // read-side chunk XOR
  const int m0 = blockIdx.y * 128, n0 = blockIdx.x * 128;
  const int wm = (w >> 1) * 64, wn = (w & 1) * 64;

  const int sr = lane >> 2;                // row within 16-row chunk
  const int sc = ((lane & 3) ^ ((sr >> 1) & 3)) * 8;   // swizzled source chunk
  const unsigned short* ga = A  + (size_t)(m0 + w * 16 + sr) * DIM + sc;
  const unsigned short* gb = Bt + (size_t)(n0 + w * 16 + sr) * DIM + sc;

  f32x4 acc[4][4] = {};

  for (int k0 = 0; k0 < DIM; k0 += 32) {
    glds16(ga + k0,            &As[w * 512]);
    glds16(ga + 64 * DIM + k0, &As[(4 + w) * 512]);
    glds16(gb + k0,            &Bs[w * 512]);
    glds16(gb + 64 * DIM + k0, &Bs[(4 + w) * 512]);
    __syncthreads();
    short8 af[4], bfr[4];
#pragma unroll
    for (int i = 0; i < 4; i++)
      af[i]  = *(const short8*)&As[(wm + i * 16 + l15) * 32 + (qd ^ asw) * 8];
#pragma unroll
    for (int i = 0; i < 4; i++)
      bfr[i] = *(const short8*)&Bs[(wn + i * 16 + l15) * 32 + (qd ^ asw) * 8];
#pragma unroll
    for (int mi = 0; mi < 4; mi++)
#pragma unroll
      for (int ni = 0; ni < 4; ni++)
        acc[mi][ni] = __builtin_amdgcn_mfma_f32_16x16x32_bf16(af[mi], bfr[ni], acc[mi][ni], 0, 0, 0);
    __syncthreads();
  }

#pragma unroll
  for (int mi = 0; mi < 4; mi++)
#pragma unroll
    for (int ni = 0; ni < 4; ni++) {
      int rowb = m0 + wm + mi * 16 + qd * 4;   // 4 consecutive rows per lane
      int col  = n0 + wn + ni * 16 + l15;
      if (EPI == 0) {
        int b = rowb >> 11, n = rowb & 2047;
        int s = col / DIM;                     // uniform per block (128 | 768)
        int rem = col - s * DIM;
        int hh = rem / DH;
        int c = rem - hh * DH;
        size_t bh = (size_t)(b * NH + hh);
        if (s == 2) {                          // V^T: 4 consecutive n at fixed c -> one 8B store
          half4 pk;
#pragma unroll
          for (int r = 0; r < 4; r++) pk[r] = (_Float16)acc[mi][ni][r];
          *(half4*)&vo[(bh * DH + c) * NSEQ + n] = pk;
        } else if (s == 0) {
#pragma unroll
          for (int r = 0; r < 4; r++)
            qo[(bh * NSEQ + n + r) * DH + c] = f2bf(acc[mi][ni][r] * 0.1472444679f); // dh^-0.5*log2e
        } else {
#pragma unroll
          for (int r = 0; r < 4; r++)
            ko[(bh * NSEQ + n + r) * DH + c] = f2bf(acc[mi][ni][r]);
        }
      } else {
#pragma unroll
        for (int r = 0; r < 4; r++)
          fo[(size_t)(rowb + r) * DIM + col] = acc[mi][ni][r] + bias[col];
      }
    }
}

// ---------------- flash attention v5: 128-q tiles + double-buffered K/V staging -----------
// One block per (b, h, 128-query tile): 512 blocks = 2/CU. K/V double-buffered (2x24.6 KB):
// ONE barrier per kt; prefetch for kt+1 issued right after the barrier and drained only at
// the next barrier (a full compute phase in flight) -> staging latency hidden.
// S^T = K·Q^T with key permutation keyof(r)=32(fk&1)+4(fk>>1)+8(m>>2)+(m&3) so lane frags
// concatenate into the K=32 f16 B-operand for PV. Row-sum via ones-A MFMA. All LDS frag
// reads XOR-swizzled conflict-free.
__global__ __launch_bounds__(256, 2) void flash_kernel(
    const unsigned short* __restrict__ Qb, const unsigned short* __restrict__ Kb,
    const _Float16* __restrict__ Vtb, unsigned short* __restrict__ Z)
{
  __shared__ unsigned char smem[49152];
  unsigned short* Qs  = (unsigned short*)smem;          // 128x96 bf16 (staging phase only)
  unsigned short* Ks0 = (unsigned short*)smem;          // buf0: K 64x96
  _Float16*       Vs0 = (_Float16*)(smem + 12288);      // buf0: V^T 96x64
  unsigned short* Ks1 = (unsigned short*)(smem + 24576);// buf1: K
  _Float16*       Vs1 = (_Float16*)(smem + 36864);      // buf1: V^T

  const int t = threadIdx.x, w = t >> 6, lane = t & 63;
  const int l15 = lane & 15, qd = lane >> 4;
  const int swz = (l15 >> 1) & 3;
  const int vswz = l15 & 7;
  const int qt = blockIdx.x, h = blockIdx.y, b = blockIdx.z;
  const size_t bh = (size_t)(b * NH + h);
  const unsigned short* Qg = Qb + (bh * NSEQ + (size_t)qt * 128) * DH;
  const unsigned short* Kg = Kb + bh * NSEQ * DH;
  const _Float16*       Vg = Vtb + bh * (size_t)DH * NSEQ;

  // Q staging: chunk L=(i*256+t) -> row r=L/12 (identity), col c holds logical c^((r>>1)&3)
  int qoff[6];
#pragma unroll
  for (int i = 0; i < 6; i++) {
    int L = i * 256 + t;
    int r = L / 12, c = L - r * 12;
    qoff[i] = r * 96 + ((c ^ ((r >> 1) & 3)) * 8);
  }
  // K staging: row r holds global key keyof(r), col swizzled
  int koff[3];
#pragma unroll
  for (int i = 0; i < 3; i++) {
    int L = w * 192 + i * 64 + lane;
    int r = L / 12, c = L - r * 12;
    int fk = r >> 4, m = r & 15;
    int key = 32 * (fk & 1) + 4 * (fk >> 1) + 8 * (m >> 2) + (m & 3);
    koff[i] = key * 96 + ((c ^ ((r >> 1) & 3)) * 8);
  }
  // V staging: chunk L=(i*256+t) -> dh-row r=L>>3, col c holds logical c^(r&7)
  int voff[3];
#pragma unroll
  for (int i = 0; i < 3; i++) {
    int L = i * 256 + t;
    int r = L >> 3, c = L & 7;
    voff[i] = r * NSEQ + ((c ^ (r & 7)) * 8);
  }

  // ---- stage Q tile (128x96), pull register-resident fragments for both q-groups ----
#pragma unroll
  for (int i = 0; i < 6; i++)
    glds16(Qg + qoff[i], &Qs[i * 2048 + w * 512]);
  __syncthreads();
  short8 qa[2][3];
#pragma unroll
  for (int fq = 0; fq < 2; fq++)
#pragma unroll
    for (int ks = 0; ks < 3; ks++)
      qa[fq][ks] = *(const short8*)&Qs[(w * 32 + fq * 16 + l15) * 96 + ((ks * 4 + qd) ^ swz) * 8];
  __syncthreads();                             // all waves done reading Qs before buf0 reuse

  // ---- prefetch kt=0 into buf0 ----
#pragma unroll
  for (int i = 0; i < 3; i++)
    glds16(Kg + koff[i], &Ks0[w * 1536 + i * 512]);
#pragma unroll
  for (int i = 0; i < 3; i++)
    glds16(Vg + voff[i], &Vs0[(i * 256 + w * 64) * 8]);

  f32x4 o[2][7] = {};                          // [fq][0..5]=O^T frags, [fq][6]=row-sum
  float mprev[2] = {-1e30f, -1e30f};           // per-lane, log2 domain
  const half8 onef = {(_Float16)1.f, (_Float16)1.f, (_Float16)1.f, (_Float16)1.f,
                      (_Float16)1.f, (_Float16)1.f, (_Float16)1.f, (_Float16)1.f};

  for (int kt = 0; kt < 32; kt++) {
    __syncthreads();                           // buf[kt&1] loads drained; prev compute done
    const unsigned short* Ks = (kt & 1) ? Ks1 : Ks0;
    const _Float16*       Vs = (kt & 1) ? Vs1 : Vs0;
    if (kt + 1 < 32) {                         // prefetch kt+1 into the other buffer
      unsigned short* Ksn = (kt & 1) ? Ks0 : Ks1;
      _Float16*       Vsn = (kt & 1) ? Vs0 : Vs1;
      const unsigned short* Kt = Kg + (size_t)(kt + 1) * 64 * DH;
      const _Float16*       Vt = Vg + (kt + 1) * 64;
#pragma unroll
      for (int i = 0; i < 3; i++)
        glds16(Kt + koff[i], &Ksn[w * 1536 + i * 512]);
#pragma unroll
      for (int i = 0; i < 3; i++)
        glds16(Vt + voff[i], &Vsn[(i * 256 + w * 64) * 8]);
    }

    // ---- S^T = K·Q^T for both q-groups: s[fq][fk][r] = key 32(fk&1)+4(fk>>1)+8qd+r ----
    f32x4 s[2][4] = {};
#pragma unroll
    for (int ks = 0; ks < 3; ks++)
#pragma unroll
      for (int fk = 0; fk < 4; fk++) {
        short8 kf = *(const short8*)&Ks[(fk * 16 + l15) * 96 + ((ks * 4 + qd) ^ swz) * 8];
        s[0][fk] = __builtin_amdgcn_mfma_f32_16x16x32_bf16(kf, qa[0][ks], s[0][fk], 0, 0, 0);
        s[1][fk] = __builtin_amdgcn_mfma_f32_16x16x32_bf16(kf, qa[1][ks], s[1][fk], 0, 0, 0);
      }

#pragma unroll
    for (int fq = 0; fq < 2; fq++) {
      // ---- online softmax, log2 domain ----
      float mx = fmaxf(fmaxf(s[fq][0][0], s[fq][0][1]), fmaxf(s[fq][0][2], s[fq][0][3]));
#pragma unroll
      for (int fk = 1; fk < 4; fk++)
        mx = fmaxf(mx, fmaxf(fmaxf(s[fq][fk][0], s[fq][fk][1]), fmaxf(s[fq][fk][2], s[fq][fk][3])));
      mx = fmaxf(mx, __shfl_xor(mx, 16, 64));
      mx = fmaxf(mx, __shfl_xor(mx, 32, 64));
      float mnew = fmaxf(mprev[fq], mx);
      float alpha = fexp2(mprev[fq] - mnew);
      mprev[fq] = mnew;

      half4 pf[4];
#pragma unroll
      for (int fk = 0; fk < 4; fk++) {
        union { fp16x2 h2[2]; half4 h4; } u;
        u.h2[0] = __builtin_amdgcn_cvt_pkrtz(fexp2(s[fq][fk][0] - mnew), fexp2(s[fq][fk][1] - mnew));
        u.h2[1] = __builtin_amdgcn_cvt_pkrtz(fexp2(s[fq][fk][2] - mnew), fexp2(s[fq][fk][3] - mnew));
        pf[fk] = u.h4;
      }
#pragma unroll
      for (int i = 0; i < 7; i++) o[fq][i] = o[fq][i] * alpha;

      // ---- O^T += V^T · P^T  (16x16x32 f16, keys p*32..p*32+31 per MFMA) ----
#pragma unroll
      for (int p = 0; p < 2; p++) {
        union { half4 h4[2]; half8 h8; } bu;
        bu.h4[0] = pf[p]; bu.h4[1] = pf[p + 2];
#pragma unroll
        for (int fc = 0; fc < 6; fc++) {
          half8 vf = *(const half8*)&Vs[(fc * 16 + l15) * 64 + ((p * 4 + qd) ^ vswz) * 8];
          o[fq][fc] = __builtin_amdgcn_mfma_f32_16x16x32_f16(vf, bu.h8, o[fq][fc], 0, 0, 0);
        }
        o[fq][6] = __builtin_amdgcn_mfma_f32_16x16x32_f16(onef, bu.h8, o[fq][6], 0, 0, 0);
      }
    }
  }

  // ---- epilogue: O/l, write Z with head-mixing reshape folded in ----
#pragma unroll
  for (int fq = 0; fq < 2; fq++) {
    float inv = 1.0f / o[fq][6][0];            // all rows of ones-frag equal the row-sum
    int q = qt * 128 + w * 32 + fq * 16 + l15;
    size_t zbase = ((size_t)b * NSEQ + h * 256 + (q >> 3)) * DIM + (q & 7) * DH;
#pragma unroll
    for (int fc = 0; fc < 6; fc++)
#pragma unroll
      for (int r = 0; r < 4; r += 2) {
        unsigned int pkd = (unsigned int)f2bf(o[fq][fc][r] * inv)
                         | ((unsigned int)f2bf(o[fq][fc][r + 1] * inv) << 16);
        *(unsigned int*)&Z[zbase + fc * 16 + qd * 4 + r] = pkd;
      }
  }
}

extern "C" void kernel_launch(void* const* d_in, const int* in_sizes, int n_in,
                              void* d_out, int out_size, void* d_ws, size_t ws_size,
                              hipStream_t stream)
{
  (void)in_sizes; (void)n_in; (void)out_size; (void)ws_size;
  const float* x    = (const float*)d_in[0];
  const float* Wqkv = (const float*)d_in[1];
  const float* Wo   = (const float*)d_in[2];
  const float* bo   = (const float*)d_in[3];
  float* out = (float*)d_out;

  unsigned short* ws    = (unsigned short*)d_ws;
  unsigned short* xb    = ws;                              // 8192*768
  unsigned short* wqkvT = xb    + (size_t)8192 * 768;      // 2304*768
  unsigned short* woT   = wqkvT + (size_t)2304 * 768;      // 768*768
  unsigned short* Qw    = woT   + (size_t)768 * 768;       // 4*8*2048*96 bf16
  unsigned short* Kw    = Qw    + (size_t)6291456;         // bf16
  _Float16*       Vw    = (_Float16*)(Kw + (size_t)6291456); // fp16 V^T
  unsigned short* Zw    = (unsigned short*)(Vw + (size_t)6291456); // 8192*768 bf16

  prep_kernel<<<8448, 256, 0, stream>>>(x, xb, Wqkv, wqkvT, Wo, woT);
  gemm_bt<0><<<dim3(18, 64), 256, 0, stream>>>(xb, wqkvT, Qw, Kw, Vw, nullptr, nullptr);
  flash_kernel<<<dim3(16, 8, 4), 256, 0, stream>>>(Qw, Kw, Vw, Zw);
  gemm_bt<1><<<dim3(6, 64), 256, 0, stream>>>(Zw, woT, nullptr, nullptr, nullptr, out, bo);
}